// Round 4
// baseline (866.621 us; speedup 1.0000x reference)
//
#include <hip/hip_runtime.h>
#include <math.h>

#define BB 8
#define NN 2048
#define KNB 20

typedef __attribute__((ext_vector_type(8))) short bf16x8;
typedef __attribute__((ext_vector_type(8))) _Float16 f16x8;
typedef __attribute__((ext_vector_type(4))) float f32x4;

__device__ inline unsigned short f2bf(float f) {
  union { float f; unsigned u; } v; v.f = f;
  unsigned r = v.u + 0x7FFF + ((v.u >> 16) & 1);  // RNE
  return (unsigned short)(r >> 16);
}

__device__ inline float lrelu(float v) { return v >= 0.f ? v : 0.2f * v; }

// ---------------------------------------------------------------- fused x-prep
template <bool F16SPLIT, bool BF16>
__global__ __launch_bounds__(256) void xprep_kernel(
    const float* __restrict__ in, int inBS, int C,
    float* __restrict__ xT, _Float16* __restrict__ hi, _Float16* __restrict__ lo,
    unsigned short* __restrict__ bf, float* __restrict__ sq) {
  __shared__ float tile[32][33];
  __shared__ float ps[8][33];
  int b = blockIdx.z;
  const float* ip = in + (size_t)b * inBS;
  int c0 = blockIdx.x * 32;   // point index n
  int r0 = blockIdx.y * 32;   // channel index
  int tx = threadIdx.x & 31, ty = threadIdx.x >> 5;
  float s = 0.f;
  for (int yy = ty; yy < 32; yy += 8) {
    int r = r0 + yy;
    float v = (r < C) ? ip[(size_t)r * NN + c0 + tx] : 0.f;
    tile[yy][tx] = v;
    s += v * v;
  }
  ps[ty][tx] = s;
  __syncthreads();
  if (ty == 0) {
    float a = ps[0][tx];
#pragma unroll
    for (int u = 1; u < 8; ++u) a += ps[u][tx];
    atomicAdd(&sq[b * NN + c0 + tx], a);
  }
  for (int yy = ty; yy < 32; yy += 8) {
    int c = c0 + yy, r = r0 + tx;   // c = n, r = channel
    if (r < C) {
      float v = tile[tx][yy];
      size_t o = (size_t)b * NN * C + (size_t)c * C + r;
      xT[o] = v;
      if (F16SPLIT) {
        _Float16 hv = (_Float16)v;
        hi[o] = hv;
        lo[o] = (_Float16)(v - (float)hv);
      }
      if (BF16) bf[o] = f2bf(v);
    }
  }
}

// ---------------------------------------------------------------- SA1 (C=3) prep
__global__ __launch_bounds__(256) void xprep3_kernel(const float* __restrict__ in,
                                                     float* __restrict__ xT,
                                                     float* __restrict__ xs4) {
  int b = blockIdx.z;
  int n = blockIdx.x * 256 + threadIdx.x;
  const float* ip = in + (size_t)b * 3 * NN;
  float x0 = ip[n], x1 = ip[NN + n], x2 = ip[2 * NN + n];
  float s = x0 * x0 + x1 * x1 + x2 * x2;
  size_t o = (size_t)b * NN + n;
  xT[o * 3 + 0] = x0; xT[o * 3 + 1] = x1; xT[o * 3 + 2] = x2;
  *(float4*)&xs4[o * 4] = make_float4(x0, x1, x2, s);
}

// ---------------------------------------------------------------- weight prep (all SAs + conv4/5 converts, one launch)
__device__ inline void mw_task(const float* __restrict__ wq, const float* __restrict__ wk,
                               const float* __restrict__ wv, const float* __restrict__ wc,
                               int C, float* __restrict__ M, float* __restrict__ WCV,
                               unsigned short* __restrict__ Mb, unsigned short* __restrict__ wcvb,
                               bool emitBF, int w, int lane) {
  int total = 2 * C * C;
  if (w >= total) return;
  float a = 0.f;
  if (w < C * C) {
    int c = w / C, cp = w - c * C;
    for (int e = lane; e < C; e += 64) a += wk[e * C + c] * wq[e * C + cp];
  } else {
    int t = w - C * C;
    int o = t / C, c = t - o * C;
    for (int e = lane; e < C; e += 64) a += wc[o * C + e] * wv[e * C + c];
  }
#pragma unroll
  for (int s = 32; s > 0; s >>= 1) a += __shfl_down(a, s);
  if (lane == 0) {
    if (w < C * C) {
      M[w] = a;
      if (emitBF) Mb[w] = f2bf(a);
    } else {
      int t = w - C * C;
      WCV[t] = a;
      if (emitBF) wcvb[t] = f2bf(a);
    }
  }
}

__global__ __launch_bounds__(256) void weight_prep_kernel(
    const float* wq1, const float* wk1, const float* wv1, const float* wc1,
    const float* wq2, const float* wk2, const float* wv2, const float* wc2,
    const float* wq3, const float* wk3, const float* wv3, const float* wc3,
    const float* wq4, const float* wk4, const float* wv4, const float* wc4,
    const float* conv4_w, const float* conv5_w,
    float* M1, float* W1, float* M2, float* W2, float* M3, float* W3, float* M4, float* W4,
    unsigned short* Mb4, unsigned short* wcvb4,
    unsigned short* w4b, unsigned short* w5b) {
  int bx = blockIdx.x;
  int lane = threadIdx.x & 63;
  int wv_ = threadIdx.x >> 6;
  if (bx < 5) {                       // SA1: 2*3*3 = 18 tasks
    mw_task(wq1, wk1, wv1, wc1, 3, M1, W1, nullptr, nullptr, false, bx * 4 + wv_, lane);
    return;
  }
  bx -= 5;
  if (bx < 2048) {                    // SA2: 2*64*64 tasks
    mw_task(wq2, wk2, wv2, wc2, 64, M2, W2, nullptr, nullptr, false, bx * 4 + wv_, lane);
    return;
  }
  bx -= 2048;
  if (bx < 2048) {                    // SA3
    mw_task(wq3, wk3, wv3, wc3, 64, M3, W3, nullptr, nullptr, false, bx * 4 + wv_, lane);
    return;
  }
  bx -= 2048;
  if (bx < 8192) {                    // SA4: 2*128*128 tasks, emit bf16
    mw_task(wq4, wk4, wv4, wc4, 128, M4, W4, Mb4, wcvb4, true, bx * 4 + wv_, lane);
    return;
  }
  bx -= 8192;
  if (bx < 256) {                     // conv4 weight convert
    int i = bx * 256 + threadIdx.x;
    w4b[i] = f2bf(conv4_w[i]);
    return;
  }
  bx -= 256;
  {                                   // conv5 weight convert (2048 blocks)
    int i = bx * 256 + threadIdx.x;
    w5b[i] = f2bf(conv5_w[i]);
  }
}

// ---------------------------------------------------------------- transpose (fp32) — SA1 only
__global__ __launch_bounds__(256) void transpose_kernel(const float* __restrict__ in, int inBS,
                                                        int R, int Cl, float* __restrict__ out) {
  __shared__ float tile[32][33];
  int b = blockIdx.z;
  const float* ip = in + (size_t)b * inBS;
  float* op = out + (size_t)b * R * Cl;
  int c0 = blockIdx.x * 32, r0 = blockIdx.y * 32;
  int tx = threadIdx.x & 31, ty = threadIdx.x >> 5;
  for (int yy = ty; yy < 32; yy += 8) {
    int r = r0 + yy, c = c0 + tx;
    tile[yy][tx] = (r < R && c < Cl) ? ip[(size_t)r * Cl + c] : 0.f;
  }
  __syncthreads();
  for (int yy = ty; yy < 32; yy += 8) {
    int c = c0 + yy, r = r0 + tx;
    if (c < Cl && r < R) op[(size_t)c * R + r] = tile[tx][yy];
  }
}

// ---------------------------------------------------------------- transpose + bf16 convert
__global__ __launch_bounds__(256) void transpose_bf16_kernel(const float* __restrict__ in, int inBS,
                                                             int R, int Cl,
                                                             unsigned short* __restrict__ out) {
  __shared__ float tile[32][33];
  int b = blockIdx.z;
  const float* ip = in + (size_t)b * inBS;
  unsigned short* op = out + (size_t)b * R * Cl;
  int c0 = blockIdx.x * 32, r0 = blockIdx.y * 32;
  int tx = threadIdx.x & 31, ty = threadIdx.x >> 5;
  for (int yy = ty; yy < 32; yy += 8) {
    int r = r0 + yy, c = c0 + tx;
    tile[yy][tx] = (r < R && c < Cl) ? ip[(size_t)r * Cl + c] : 0.f;
  }
  __syncthreads();
  for (int yy = ty; yy < 32; yy += 8) {
    int c = c0 + yy, r = r0 + tx;
    if (c < Cl && r < R) op[(size_t)c * R + r] = f2bf(tile[tx][yy]);
  }
}

// ---------------------------------------------------------------- MFMA GEMM (bf16), async global->LDS double-buffered
// Staging via global_load_lds width=16 (linear LDS dest = tid*16B satisfies the
// wave-uniform-base + lane*16 constraint). One barrier per K-step; next tile's
// loads stay in flight under the MFMAs. launch_bounds 3 blocks/CU (LDS 32KB).
// TOUT: write output transposed as Z[n][o]. STATS: per-channel sum/sumsq.
template <bool TOUT, bool STATS>
__global__ __launch_bounds__(256, 3) void mfma_gemm_lds_kernel(
    const unsigned short* __restrict__ A, const unsigned short* __restrict__ B,
    float* __restrict__ Z, int O, int K, float* __restrict__ gstats) {
  const int b = blockIdx.z;
  const int n0 = blockIdx.x * 128, o0 = blockIdx.y * 128;
  const int tid = threadIdx.x;
  const int wave = tid >> 6, lane = tid & 63;
  const int wo = wave >> 1, wn = wave & 1;
  const int l16 = lane & 15, q = lane >> 4;
  __shared__ unsigned short Al[2][4096];
  __shared__ unsigned short Bl[2][4096];
  const unsigned short* Ab = A + (size_t)o0 * K;
  const unsigned short* Bb = B + ((size_t)b * NN + n0) * K;

  const int p0 = tid, p1 = tid + 256;
  const int r0 = ((p0 >> 6) << 4) | (p0 & 15), c0 = ((p0 >> 4) & 3) * 8;
  const int r1 = ((p1 >> 6) << 4) | (p1 & 15), c1 = ((p1 >> 4) & 3) * 8;

  auto glds = [&](int buf, int k0) {
    __builtin_amdgcn_global_load_lds((const unsigned int*)(Ab + (size_t)r0 * K + k0 + c0),
                                     (unsigned int*)&Al[buf][p0 * 8], 16, 0, 0);
    __builtin_amdgcn_global_load_lds((const unsigned int*)(Ab + (size_t)r1 * K + k0 + c1),
                                     (unsigned int*)&Al[buf][p1 * 8], 16, 0, 0);
    __builtin_amdgcn_global_load_lds((const unsigned int*)(Bb + (size_t)r0 * K + k0 + c0),
                                     (unsigned int*)&Bl[buf][p0 * 8], 16, 0, 0);
    __builtin_amdgcn_global_load_lds((const unsigned int*)(Bb + (size_t)r1 * K + k0 + c1),
                                     (unsigned int*)&Bl[buf][p1 * 8], 16, 0, 0);
  };

  f32x4 acc[4][4];
#pragma unroll
  for (int s = 0; s < 4; ++s)
#pragma unroll
    for (int t = 0; t < 4; ++t) acc[s][t] = (f32x4){0.f, 0.f, 0.f, 0.f};

  glds(0, 0);
  int cur = 0;
  for (int k0 = 0; k0 < K; k0 += 32) {
    __syncthreads();                       // drains vmcnt -> buf[cur] ready
    if (k0 + 32 < K) glds(cur ^ 1, k0 + 32);  // async into other buffer
    bf16x8 af[4], bfr[4];
#pragma unroll
    for (int s = 0; s < 4; ++s)
      af[s] = *(const bf16x8*)&Al[cur][((wo * 4 + s) * 64 + q * 16 + l16) * 8];
#pragma unroll
    for (int t = 0; t < 4; ++t)
      bfr[t] = *(const bf16x8*)&Bl[cur][((wn * 4 + t) * 64 + q * 16 + l16) * 8];
#pragma unroll
    for (int s = 0; s < 4; ++s)
#pragma unroll
      for (int t = 0; t < 4; ++t)
        acc[s][t] = __builtin_amdgcn_mfma_f32_16x16x32_bf16(af[s], bfr[t], acc[s][t], 0, 0, 0);
    cur ^= 1;
  }
#pragma unroll
  for (int s = 0; s < 4; ++s)
#pragma unroll
    for (int t = 0; t < 4; ++t) {
      if (TOUT) {
        int n = n0 + wn * 64 + t * 16 + l16;
        int ob = o0 + wo * 64 + s * 16 + q * 4;
        *(f32x4*)&Z[((size_t)b * NN + n) * O + ob] = acc[s][t];
      } else {
        float* zp = Z + ((size_t)b * O + o0 + wo * 64 + s * 16 + q * 4) * NN
                    + n0 + wn * 64 + t * 16 + l16;
#pragma unroll
        for (int r = 0; r < 4; ++r) zp[(size_t)r * NN] = acc[s][t][r];
      }
    }
  if (STATS) {
    float psum[16], psq[16];
#pragma unroll
    for (int s = 0; s < 4; ++s)
#pragma unroll
      for (int r = 0; r < 4; ++r) {
        float a = 0.f, sa = 0.f;
#pragma unroll
        for (int t = 0; t < 4; ++t) { float v = acc[s][t][r]; a += v; sa += v * v; }
        psum[s * 4 + r] = a; psq[s * 4 + r] = sa;
      }
#pragma unroll
    for (int i = 0; i < 16; ++i) {
#pragma unroll
      for (int mm = 1; mm < 16; mm <<= 1) {
        psum[i] += __shfl_xor(psum[i], mm);
        psq[i] += __shfl_xor(psq[i], mm);
      }
    }
    __syncthreads();                 // staging LDS no longer needed
    float* sb = (float*)&Al[0][0];   // 128 ch x {sum,sq}
    sb[tid] = 0.f;
    __syncthreads();
    if (l16 == 0) {
#pragma unroll
      for (int i = 0; i < 16; ++i) {
        int ch = wo * 64 + (i >> 2) * 16 + q * 4 + (i & 3);
        atomicAdd(&sb[ch * 2], psum[i]);
        atomicAdd(&sb[ch * 2 + 1], psq[i]);
      }
    }
    __syncthreads();
    atomicAdd(&gstats[o0 * 2 + tid], sb[tid]);
  }
}

// ---------------------------------------------------------------- pd via f16 split MFMA, symmetric tiles,
// async global->LDS double-buffered (same glds structure as the GEMM above).
__global__ __launch_bounds__(256, 2) void pd_mfma_sym_kernel(
    const _Float16* __restrict__ xhi, const _Float16* __restrict__ xlo, int C,
    const float* __restrict__ sq, float* __restrict__ P, int b_base) {
  const int bl = blockIdx.y;
  const int b = b_base + bl;
  int ti = 0, xx = blockIdx.x;
  while (xx >= 16 - ti) { xx -= 16 - ti; ++ti; }
  const int tj = ti + xx;
  const int n0 = ti * 128, m0 = tj * 128;
  const int tid = threadIdx.x;
  const int wave = tid >> 6, lane = tid & 63;
  const int wn_ = wave >> 1, wm_ = wave & 1;
  const int l16 = lane & 15, q = lane >> 4;
  __shared__ _Float16 Ah[2][4096], Alo[2][4096], Bh[2][4096], Blo[2][4096];
  const _Float16* Ahg = xhi + ((size_t)b * NN + n0) * C;
  const _Float16* Alg = xlo + ((size_t)b * NN + n0) * C;
  const _Float16* Bhg = xhi + ((size_t)b * NN + m0) * C;
  const _Float16* Blg = xlo + ((size_t)b * NN + m0) * C;

  const int p0 = tid, p1 = tid + 256;
  const int r0 = ((p0 >> 6) << 4) | (p0 & 15), c0 = ((p0 >> 4) & 3) * 8;
  const int r1 = ((p1 >> 6) << 4) | (p1 & 15), c1 = ((p1 >> 4) & 3) * 8;

  auto glds = [&](int buf, int k0) {
    __builtin_amdgcn_global_load_lds((const unsigned int*)(Ahg + (size_t)r0 * C + k0 + c0),
                                     (unsigned int*)&Ah[buf][p0 * 8], 16, 0, 0);
    __builtin_amdgcn_global_load_lds((const unsigned int*)(Ahg + (size_t)r1 * C + k0 + c1),
                                     (unsigned int*)&Ah[buf][p1 * 8], 16, 0, 0);
    __builtin_amdgcn_global_load_lds((const unsigned int*)(Alg + (size_t)r0 * C + k0 + c0),
                                     (unsigned int*)&Alo[buf][p0 * 8], 16, 0, 0);
    __builtin_amdgcn_global_load_lds((const unsigned int*)(Alg + (size_t)r1 * C + k0 + c1),
                                     (unsigned int*)&Alo[buf][p1 * 8], 16, 0, 0);
    __builtin_amdgcn_global_load_lds((const unsigned int*)(Bhg + (size_t)r0 * C + k0 + c0),
                                     (unsigned int*)&Bh[buf][p0 * 8], 16, 0, 0);
    __builtin_amdgcn_global_load_lds((const unsigned int*)(Bhg + (size_t)r1 * C + k0 + c1),
                                     (unsigned int*)&Bh[buf][p1 * 8], 16, 0, 0);
    __builtin_amdgcn_global_load_lds((const unsigned int*)(Blg + (size_t)r0 * C + k0 + c0),
                                     (unsigned int*)&Blo[buf][p0 * 8], 16, 0, 0);
    __builtin_amdgcn_global_load_lds((const unsigned int*)(Blg + (size_t)r1 * C + k0 + c1),
                                     (unsigned int*)&Blo[buf][p1 * 8], 16, 0, 0);
  };

  f32x4 acc[4][4];
#pragma unroll
  for (int s = 0; s < 4; ++s)
#pragma unroll
    for (int t = 0; t < 4; ++t) acc[s][t] = (f32x4){0.f, 0.f, 0.f, 0.f};

  glds(0, 0);
  int cur = 0;
  for (int k0 = 0; k0 < C; k0 += 32) {
    __syncthreads();
    if (k0 + 32 < C) glds(cur ^ 1, k0 + 32);
    f16x8 ah[4], al[4], bh[4], blv[4];
#pragma unroll
    for (int s = 0; s < 4; ++s) {
      int pi = ((wn_ * 4 + s) * 64 + q * 16 + l16) * 8;
      ah[s] = *(const f16x8*)&Ah[cur][pi];
      al[s] = *(const f16x8*)&Alo[cur][pi];
    }
#pragma unroll
    for (int t = 0; t < 4; ++t) {
      int pi = ((wm_ * 4 + t) * 64 + q * 16 + l16) * 8;
      bh[t] = *(const f16x8*)&Bh[cur][pi];
      blv[t] = *(const f16x8*)&Blo[cur][pi];
    }
#pragma unroll
    for (int s = 0; s < 4; ++s)
#pragma unroll
      for (int t = 0; t < 4; ++t) {
        acc[s][t] = __builtin_amdgcn_mfma_f32_16x16x32_f16(ah[s], bh[t], acc[s][t], 0, 0, 0);
        acc[s][t] = __builtin_amdgcn_mfma_f32_16x16x32_f16(ah[s], blv[t], acc[s][t], 0, 0, 0);
        acc[s][t] = __builtin_amdgcn_mfma_f32_16x16x32_f16(al[s], bh[t], acc[s][t], 0, 0, 0);
      }
    cur ^= 1;
  }
  // normal tile: rows in i-block, cols in j-block, minus sq[col]
#pragma unroll
  for (int s = 0; s < 4; ++s)
#pragma unroll
    for (int t = 0; t < 4; ++t) {
      int col = m0 + wm_ * 64 + t * 16 + l16;
      float sqv = sq[b * NN + col];
      float* pp = P + ((size_t)bl * NN + n0 + wn_ * 64 + s * 16 + q * 4) * NN + col;
#pragma unroll
      for (int r = 0; r < 4; ++r) pp[(size_t)r * NN] = 2.f * acc[s][t][r] - sqv;
    }
  // mirrored tile: rows in j-block, cols in i-block, minus sq[col=n]
  if (ti != tj) {
#pragma unroll
    for (int s = 0; s < 4; ++s) {
      int nb = n0 + wn_ * 64 + s * 16 + q * 4;
      float4 sqn = *(const float4*)&sq[b * NN + nb];
#pragma unroll
      for (int t = 0; t < 4; ++t) {
        int m = m0 + wm_ * 64 + t * 16 + l16;
        f32x4 ov;
        ov[0] = 2.f * acc[s][t][0] - sqn.x;
        ov[1] = 2.f * acc[s][t][1] - sqn.y;
        ov[2] = 2.f * acc[s][t][2] - sqn.z;
        ov[3] = 2.f * acc[s][t][3] - sqn.w;
        *(f32x4*)&P[((size_t)bl * NN + m) * NN + nb] = ov;
      }
    }
  }
}

// ---------------------------------------------------------------- top-20: slot-packed u32 bitonic
__global__ __launch_bounds__(256) void topk_bsort_kernel(const float* __restrict__ P,
                                                         int* __restrict__ idx_out, int b_base) {
  const int wave = threadIdx.x >> 6;
  const int lane = threadIdx.x & 63;
  const int n = blockIdx.x * 4 + wave;
  const int bl = blockIdx.y;
  const int b = b_base + bl;
  const float4* rp = (const float4*)(P + ((size_t)bl * NN + n) * NN);
  unsigned key[32];
#pragma unroll
  for (int q = 0; q < 8; ++q) {
    float4 vv = rp[q * 64 + lane];
    int mb = q * 256 + lane * 4;
    float fv[4] = {vv.x, vv.y, vv.z, vv.w};
#pragma unroll
    for (int j = 0; j < 4; ++j) {
      unsigned u = __float_as_uint(fv[j]);
      unsigned mask = (unsigned)(((int)u) >> 31) | 0x80000000u;
      unsigned sl = (unsigned)(q * 4 + j);
      key[q * 4 + j] = (mb + j == n) ? sl : (((u ^ mask) & 0xFFFFFFE0u) | sl);
    }
  }
#pragma unroll
  for (int k = 2; k <= 32; k <<= 1) {
#pragma unroll
    for (int j = k >> 1; j > 0; j >>= 1) {
#pragma unroll
      for (int i = 0; i < 32; ++i) {
        int l = i ^ j;
        if (l > i) {
          unsigned ka = key[i], kb = key[l];
          unsigned mx = ka > kb ? ka : kb;
          unsigned mn = ka > kb ? kb : ka;
          if ((i & k) == 0) { key[i] = mx; key[l] = mn; }
          else              { key[i] = mn; key[l] = mx; }
        }
      }
    }
  }
  int* op = idx_out + (size_t)(b * NN + n) * KNB;
  for (int k = 0; k < KNB; ++k) {
    unsigned best = key[0];
#pragma unroll
    for (int s = 32; s > 0; s >>= 1) {
      unsigned o = (unsigned)__shfl_xor((int)best, s);
      best = best > o ? best : o;
    }
    unsigned long long bal = __ballot(key[0] == best);
    if (lane == (int)__ffsll(bal) - 1) {
      unsigned sl = key[0] & 31u;
      op[k] = (int)((sl >> 2) * 256u + (unsigned)lane * 4u + (sl & 3u));
#pragma unroll
      for (int j = 0; j < 20; ++j) key[j] = key[j + 1];
    }
  }
}

// ---------------------------------------------------------------- SA1 fused distance + top-20 (C=3)
__global__ __launch_bounds__(256) void topk_c3_kernel(const float* __restrict__ xs4,
                                                      int* __restrict__ idx_out) {
  const int wave = threadIdx.x >> 6;
  const int lane = threadIdx.x & 63;
  const int n = blockIdx.x * 4 + wave;
  const int b = blockIdx.y;
  const float4* xp = (const float4*)(xs4 + (size_t)b * NN * 4);
  float4 me = xp[n];
  float tx = 2.f * me.x, ty = 2.f * me.y, tz = 2.f * me.z;
  unsigned key[32];
#pragma unroll
  for (int s = 0; s < 32; ++s) {
    int m = s * 64 + lane;
    float4 c = xp[m];
    float pd = tx * c.x + ty * c.y + tz * c.z - c.w;
    unsigned u = __float_as_uint(pd);
    unsigned mask = (unsigned)(((int)u) >> 31) | 0x80000000u;
    key[s] = (m == n) ? (unsigned)s : ((((u ^ mask) & 0xFFFFFFE0u)) | (unsigned)s);
  }
#pragma unroll
  for (int k = 2; k <= 32; k <<= 1) {
#pragma unroll
    for (int j = k >> 1; j > 0; j >>= 1) {
#pragma unroll
      for (int i = 0; i < 32; ++i) {
        int l = i ^ j;
        if (l > i) {
          unsigned ka = key[i], kb = key[l];
          unsigned mx = ka > kb ? ka : kb;
          unsigned mn = ka > kb ? kb : ka;
          if ((i & k) == 0) { key[i] = mx; key[l] = mn; }
          else              { key[i] = mn; key[l] = mx; }
        }
      }
    }
  }
  int* op = idx_out + (size_t)(b * NN + n) * KNB;
  for (int k = 0; k < KNB; ++k) {
    unsigned best = key[0];
#pragma unroll
    for (int s = 32; s > 0; s >>= 1) {
      unsigned o = (unsigned)__shfl_xor((int)best, s);
      best = best > o ? best : o;
    }
    unsigned long long bal = __ballot(key[0] == best);
    if (lane == (int)__ffsll(bal) - 1) {
      unsigned sl = key[0] & 31u;
      op[k] = (int)(sl * 64u + (unsigned)lane);
#pragma unroll
      for (int j = 0; j < 20; ++j) key[j] = key[j + 1];
    }
  }
}

// ---------------------------------------------------------------- conv GEMM 64-tile (small O)
template <bool BT, bool TOUT>
__global__ __launch_bounds__(256, 2) void conv_gemm_kernel(
    const float* __restrict__ in, int inBS, int C, int O,
    const float* __restrict__ w, float* __restrict__ z) {
  const int b = blockIdx.z;
  const int n0 = blockIdx.x * 64, o0 = blockIdx.y * 64;
  const int tid = threadIdx.x;
  const int tm = tid & 15, tn = tid >> 4;
  __shared__ float Ws[16][68];
  __shared__ float Xs[16][64];
  const float* ib = in + (size_t)b * inBS;
  float acc[4][4];
#pragma unroll
  for (int i = 0; i < 4; ++i)
#pragma unroll
    for (int j = 0; j < 4; ++j) acc[i][j] = 0.f;

  for (int k0 = 0; k0 < C; k0 += 16) {
    __syncthreads();
#pragma unroll
    for (int it = 0; it < 4; ++it) {
      int i = it * 256 + tid;
      if (BT) {
        int kc = i & 15, nl = i >> 4;
        Xs[kc][nl] = ((k0 + kc) < C) ? ib[(size_t)(n0 + nl) * C + k0 + kc] : 0.f;
      } else {
        int kc = i >> 6, nl = i & 63;
        Xs[kc][nl] = ((k0 + kc) < C) ? ib[(size_t)(k0 + kc) * NN + n0 + nl] : 0.f;
      }
      int ol = i >> 4, kc2 = i & 15;
      Ws[kc2][ol] = ((o0 + ol) < O && (k0 + kc2) < C) ? w[(size_t)(o0 + ol) * C + k0 + kc2] : 0.f;
    }
    __syncthreads();
#pragma unroll
    for (int kc = 0; kc < 16; ++kc) {
      float4 a = *(const float4*)&Ws[kc][tn * 4];
      float4 bv = *(const float4*)&Xs[kc][tm * 4];
      acc[0][0] += a.x * bv.x; acc[0][1] += a.x * bv.y; acc[0][2] += a.x * bv.z; acc[0][3] += a.x * bv.w;
      acc[1][0] += a.y * bv.x; acc[1][1] += a.y * bv.y; acc[1][2] += a.y * bv.z; acc[1][3] += a.y * bv.w;
      acc[2][0] += a.z * bv.x; acc[2][1] += a.z * bv.y; acc[2][2] += a.z * bv.z; acc[2][3] += a.z * bv.w;
      acc[3][0] += a.w * bv.x; acc[3][1] += a.w * bv.y; acc[3][2] += a.w * bv.z; acc[3][3] += a.w * bv.w;
    }
  }
  if (TOUT) {
#pragma unroll
    for (int j = 0; j < 4; ++j) {
      int n = n0 + tm * 4 + j;
      int ob = o0 + tn * 4;
      if (ob < O) {
        float4 ov;
        ov.x = acc[0][j]; ov.y = acc[1][j]; ov.z = acc[2][j]; ov.w = acc[3][j];
        *(float4*)&z[((size_t)b * NN + n) * O + ob] = ov;
      }
    }
  } else {
#pragma unroll
    for (int i = 0; i < 4; ++i) {
      int o = o0 + tn * 4 + i;
      if (o < O) {
        float4 ov;
        ov.x = acc[i][0]; ov.y = acc[i][1]; ov.z = acc[i][2]; ov.w = acc[i][3];
        *(float4*)&z[((size_t)b * O + o) * NN + n0 + tm * 4] = ov;
      }
    }
  }
}

// ---------------------------------------------------------------- conv GEMM 128-tile, double-buffered (fp32)
__global__ __launch_bounds__(256, 2) void conv_gemm128_db_kernel(
    const float* __restrict__ in, int inBS, int C, int O,
    const float* __restrict__ w, float* __restrict__ z) {
  const int b = blockIdx.z;
  const int n0 = blockIdx.x * 128, o0 = blockIdx.y * 128;
  const int tid = threadIdx.x;
  const int tm = tid & 15, tn = tid >> 4;
  __shared__ float Xs[2][16][128];
  __shared__ float Ws[2][16][132];
  const float* ib = in + (size_t)b * inBS;
  float acc[8][8];
#pragma unroll
  for (int i = 0; i < 8; ++i)
#pragma unroll
    for (int j = 0; j < 8; ++j) acc[i][j] = 0.f;

  float4 xr[2], wr[2];
  auto load_tile = [&](int k0) {
#pragma unroll
    for (int it = 0; it < 2; ++it) {
      int i = it * 256 + tid;
      int kc = i >> 5, c4 = i & 31;
      xr[it] = ((k0 + kc) < C) ? *(const float4*)&ib[(size_t)(k0 + kc) * NN + n0 + c4 * 4]
                               : make_float4(0.f, 0.f, 0.f, 0.f);
      int ol = i >> 2, kq = i & 3;
      wr[it] = ((k0 + kq * 4) < C) ? *(const float4*)&w[(size_t)(o0 + ol) * C + k0 + kq * 4]
                                   : make_float4(0.f, 0.f, 0.f, 0.f);
    }
  };
  auto store_tile = [&](int buf) {
#pragma unroll
    for (int it = 0; it < 2; ++it) {
      int i = it * 256 + tid;
      int kc = i >> 5, c4 = i & 31;
      *(float4*)&Xs[buf][kc][c4 * 4] = xr[it];
      int ol = i >> 2, kq = i & 3;
      Ws[buf][kq * 4 + 0][ol] = wr[it].x;
      Ws[buf][kq * 4 + 1][ol] = wr[it].y;
      Ws[buf][kq * 4 + 2][ol] = wr[it].z;
      Ws[buf][kq * 4 + 3][ol] = wr[it].w;
    }
  };

  load_tile(0);
  store_tile(0);
  int cur = 0;
  for (int k0 = 0; k0 < C; k0 += 16) {
    bool more = (k0 + 16) < C;
    if (more) load_tile(k0 + 16);
    __syncthreads();
#pragma unroll
    for (int kc = 0; kc < 16; ++kc) {
      float4 a0 = *(const float4*)&Ws[cur][kc][tn * 4];
      float4 a1 = *(const float4*)&Ws[cur][kc][64 + tn * 4];
      float4 b0 = *(const float4*)&Xs[cur][kc][tm * 4];
      float4 b1 = *(const float4*)&Xs[cur][kc][64 + tm * 4];
      float ar[8] = {a0.x, a0.y, a0.z, a0.w, a1.x, a1.y, a1.z, a1.w};
      float br[8] = {b0.x, b0.y, b0.z, b0.w, b1.x, b1.y, b1.z, b1.w};
#pragma unroll
      for (int i = 0; i < 8; ++i)
#pragma unroll
        for (int j = 0; j < 8; ++j) acc[i][j] += ar[i] * br[j];
    }
    if (more) store_tile(cur ^ 1);
    cur ^= 1;
  }
#pragma unroll
  for (int h = 0; h < 2; ++h)
#pragma unroll
    for (int i = 0; i < 4; ++i) {
      int r = h * 4 + i;
      int o = o0 + h * 64 + tn * 4 + i;
      float* zrow = &z[((size_t)b * O + o) * NN + n0];
      float4 o0v, o1v;
      o0v.x = acc[r][0]; o0v.y = acc[r][1]; o0v.z = acc[r][2]; o0v.w = acc[r][3];
      o1v.x = acc[r][4]; o1v.y = acc[r][5]; o1v.z = acc[r][6]; o1v.w = acc[r][7];
      *(float4*)&zrow[tm * 4] = o0v;
      *(float4*)&zrow[64 + tm * 4] = o1v;
    }
}

// ---------------------------------------------------------------- attention, register-resident (C=64/128)
template <int C, bool BF16OUT>
__global__ __launch_bounds__(256) void att_wave_reg_kernel(
    const float* __restrict__ xT, const float* __restrict__ UT,
    const int* __restrict__ idx, float* __restrict__ AGGt,
    unsigned short* __restrict__ AGGtb) {
  const int lane = threadIdx.x & 63;
  const int gid = blockIdx.x * 4 + (threadIdx.x >> 6);   // = b*NN + n
  const int n = gid & (NN - 1);
  const int b = gid >> 11;
  const float* xTb = xT + (size_t)b * NN * C;
  int nv = idx[(size_t)gid * KNB + (lane < KNB ? lane : 0)];
  float u0 = UT[(size_t)gid * C + lane];
  float u1;
  if (C == 128) u1 = UT[(size_t)gid * C + 64 + lane];
  float v0[KNB], v1[KNB], p[KNB];
#pragma unroll
  for (int k = 0; k < KNB; ++k) {
    int m = __shfl(nv, k) & (NN - 1);
    v0[k] = xTb[(size_t)m * C + lane];
    if (C == 128) v1[k] = xTb[(size_t)m * C + 64 + lane];
  }
#pragma unroll
  for (int k = 0; k < KNB; ++k) {
    float a = v0[k] * u0;
    if (C == 128) a += v1[k] * u1;
    p[k] = a;
  }
#pragma unroll
  for (int k = 0; k < KNB; ++k) {
#pragma unroll
    for (int s = 32; s > 0; s >>= 1) p[k] += __shfl_xor(p[k], s);
  }
  const float scale = (C == 128) ? 0.088388347648318447f : 0.125f;  // 1/sqrt(C)
  float mx = p[0];
#pragma unroll
  for (int k = 1; k < KNB; ++k) mx = fmaxf(mx, p[k]);
  float sum = 0.f;
#pragma unroll
  for (int k = 0; k < KNB; ++k) {
    p[k] = expf((p[k] - mx) * scale);
    sum += p[k];
  }
  float inv = 1.f / sum;
  float a0 = 0.f, a1 = 0.f;
#pragma unroll
  for (int k = 0; k < KNB; ++k) {
    a0 += p[k] * v0[k];
    if (C == 128) a1 += p[k] * v1[k];
  }
  float r0 = a0 * inv - xTb[(size_t)n * C + lane];
  float r1;
  if (C == 128) r1 = a1 * inv - xTb[(size_t)n * C + 64 + lane];
  if (BF16OUT) {
    AGGtb[(size_t)gid * C + lane] = f2bf(r0);
    if (C == 128) AGGtb[(size_t)gid * C + 64 + lane] = f2bf(r1);
  } else {
    AGGt[(size_t)gid * C + lane] = r0;
    if (C == 128) AGGt[(size_t)gid * C + 64 + lane] = r1;
  }
}

// ---------------------------------------------------------------- attention (wave/point) — SA1 C=3 only
template <int C, bool BF16OUT>
__global__ __launch_bounds__(64) void att_wave_kernel(
    const float* __restrict__ xT, const float* __restrict__ UT,
    const int* __restrict__ idx, float* __restrict__ AGGt,
    unsigned short* __restrict__ AGGtb) {
  const int n = blockIdx.x & (NN - 1);
  const int b = blockIdx.x >> 11;
  const int lane = threadIdx.x;
  constexpr int CP = C + 1;
  __shared__ float nb[KNB][CP];
  __shared__ float sl[KNB];
  __shared__ int nidx[KNB];
  __shared__ float ul[C];
  const float* xTb = xT + (size_t)b * NN * C;
  if (lane < KNB) nidx[lane] = idx[(size_t)(b * NN + n) * KNB + lane] & (NN - 1);
  for (int c = lane; c < C; c += 64) ul[c] = UT[((size_t)b * NN + n) * C + c];
  __syncthreads();
  for (int i = lane; i < KNB * C; i += 64) {
    int k = i / C, c = i - k * C;
    nb[k][c] = xTb[(size_t)nidx[k] * C + c];
  }
  __syncthreads();
  float sv = -INFINITY;
  if (lane < KNB) {
    float a = 0.f;
#pragma unroll
    for (int c = 0; c < C; ++c) a += nb[lane][c] * ul[c];
    sv = a / sqrtf((float)C);
  }
  float mx = sv;
#pragma unroll
  for (int s = 32; s > 0; s >>= 1) mx = fmaxf(mx, __shfl_xor(mx, s));
  float e = (lane < KNB) ? expf(sv - mx) : 0.f;
  float sum = e;
#pragma unroll
  for (int s = 32; s > 0; s >>= 1) sum += __shfl_xor(sum, s);
  if (lane < KNB) sl[lane] = e / sum;
  __syncthreads();
  const float* xTn = xTb + (size_t)n * C;
  for (int c = lane; c < C; c += 64) {
    float a = 0.f;
#pragma unroll
    for (int k = 0; k < KNB; ++k) a += sl[k] * nb[k][c];
    float r = a - xTn[c];
    if (BF16OUT)
      AGGtb[((size_t)b * NN + n) * C + c] = f2bf(r);
    else
      AGGt[((size_t)b * NN + n) * C + c] = r;
  }
}

// ---------------------------------------------------------------- fused BN (+LReLU), float4
// PRE: stats precomputed by GEMM epilogue (gs[o*2]=sum, gs[o*2+1]=sumsq).
template <bool PRE>
__global__ __launch_bounds__(256) void bn_fused_kernel(const float* __restrict__ z, int O,
                                                       float* __restrict__ out, int outBS, int c0,
                                                       const float* __restrict__ gs) {
  int o = blockIdx.x;
  int tid = threadIdx.x;
  float m, r;
  if (PRE) {
    float s = gs[o * 2], s2 = gs[o * 2 + 1];
    m = s / (BB * NN);
    float var = s2 / (BB * NN) - m * m;
    r = rsqrtf(var + 1e-5f);
  } else {
    __shared__ float s1[256], s2[256];
    __shared__ float smv, srv;
    float a1 = 0.f, a2 = 0.f;
    for (int i = tid; i < BB * 512; i += 256) {
      int b = i >> 9, n4 = i & 511;
      float4 v = *(const float4*)&z[((size_t)b * O + o) * NN + n4 * 4];
      a1 += v.x + v.y + v.z + v.w;
      a2 += v.x * v.x + v.y * v.y + v.z * v.z + v.w * v.w;
    }
    s1[tid] = a1; s2[tid] = a2;
    __syncthreads();
    for (int st = 128; st > 0; st >>= 1) {
      if (tid < st) { s1[tid] += s1[tid + st]; s2[tid] += s2[tid + st]; }
      __syncthreads();
    }
    if (tid == 0) {
      float mm = s1[0] / (BB * NN);
      float var = s2[0] / (BB * NN) - mm * mm;
      smv = mm; srv = rsqrtf(var + 1e-5f);
    }
    __syncthreads();
    m = smv; r = srv;
  }
  for (int i = tid; i < BB * 512; i += 256) {
    int b = i >> 9, n4 = i & 511;
    float4 v = *(const float4*)&z[((size_t)b * O + o) * NN + n4 * 4];
    float4 ov;
    ov.x = lrelu((v.x - m) * r); ov.y = lrelu((v.y - m) * r);
    ov.z = lrelu((v.z - m) * r); ov.w = lrelu((v.w - m) * r);
    *(float4*)&out[(size_t)b * outBS + (size_t)(c0 + o) * NN + n4 * 4] = ov;
  }
}

// ---------------------------------------------------------------- BN+LReLU into h[:,0:O,:], copy xin into h[:,O:2O,:], float4
__global__ __launch_bounds__(256) void bn_copy_kernel(const float* __restrict__ z, int O,
                                                      const float* __restrict__ xin, int xbs,
                                                      float* __restrict__ out) {
  int o = blockIdx.x;  // 0..2O-1
  int tid = threadIdx.x;
  int outBS = 2 * O * NN;
  if (o >= O) {
    int c = o - O;
    for (int i = tid; i < BB * 512; i += 256) {
      int b = i >> 9, n4 = i & 511;
      *(float4*)&out[(size_t)b * outBS + (size_t)o * NN + n4 * 4] =
          *(const float4*)&xin[(size_t)b * xbs + (size_t)c * NN + n4 * 4];
    }
    return;
  }
  __shared__ float s1[256], s2[256];
  __shared__ float smv, srv;
  float a1 = 0.f, a2 = 0.f;
  for (int i = tid; i < BB * 512; i += 256) {
    int b = i >> 9, n4 = i & 511;
    float4 v = *(const float4*)&z[((size_t)b * O + o) * NN + n4 * 4];
    a1 += v.x + v.y + v.z + v.w;
    a2 += v.x * v.x + v.y * v.y + v.z * v.z + v.w * v.w;
  }
  s1[tid] = a1; s2[tid] = a2;
  __syncthreads();
  for (int st = 128; st > 0; st >>= 1) {
    if (tid < st) { s1[tid] += s1[tid + st]; s2[tid] += s2[tid + st]; }
    __syncthreads();
  }
  if (tid == 0) {
    float m = s1[0] / (BB * NN);
    float var = s2[0] / (BB * NN) - m * m;
    smv = m; srv = rsqrtf(var + 1e-5f);
  }
  __syncthreads();
  float m = smv, r = srv;
  for (int i = tid; i < BB * 512; i += 256) {
    int b = i >> 9, n4 = i & 511;
    float4 v = *(const float4*)&z[((size_t)b * O + o) * NN + n4 * 4];
    float4 ov;
    ov.x = lrelu((v.x - m) * r); ov.y = lrelu((v.y - m) * r);
    ov.z = lrelu((v.z - m) * r); ov.w = lrelu((v.w - m) * r);
    *(float4*)&out[(size_t)b * outBS + (size_t)o * NN + n4 * 4] = ov;
  }
}

// ---------------------------------------------------------------- fused BN+LReLU+max/mean pool (conv5), float4
template <bool PRE>
__global__ __launch_bounds__(256) void bn_pool_kernel(const float* __restrict__ z,
                                                      float* __restrict__ p,
                                                      const float* __restrict__ gs) {
  int o = blockIdx.x;
  int tid = threadIdx.x;
  float m, r;
  if (PRE) {
    float s = gs[o * 2], s2 = gs[o * 2 + 1];
    m = s / (BB * NN);
    float var = s2 / (BB * NN) - m * m;
    r = rsqrtf(var + 1e-5f);
  } else {
    __shared__ float s1[256], s2[256];
    __shared__ float smv, srv;
    float a1 = 0.f, a2 = 0.f;
    for (int i = tid; i < BB * 512; i += 256) {
      int b = i >> 9, n4 = i & 511;
      float4 v = *(const float4*)&z[((size_t)b * 1024 + o) * NN + n4 * 4];
      a1 += v.x + v.y + v.z + v.w;
      a2 += v.x * v.x + v.y * v.y + v.z * v.z + v.w * v.w;
    }
    s1[tid] = a1; s2[tid] = a2;
    __syncthreads();
    for (int st = 128; st > 0; st >>= 1) {
      if (tid < st) { s1[tid] += s1[tid + st]; s2[tid] += s2[tid + st]; }
      __syncthreads();
    }
    if (tid == 0) {
      float mm = s1[0] / (BB * NN);
      float var = s2[0] / (BB * NN) - mm * mm;
      smv = mm; srv = rsqrtf(var + 1e-5f);
    }
    __syncthreads();
    m = smv; r = srv;
  }
  int b = tid >> 5, l = tid & 31;
  const float* zp = z + ((size_t)b * 1024 + o) * NN;
  float mx = -INFINITY, sm = 0.f;
  for (int j = l; j < 512; j += 32) {
    float4 v = *(const float4*)&zp[j * 4];
    float vx = lrelu((v.x - m) * r), vy = lrelu((v.y - m) * r);
    float vz = lrelu((v.z - m) * r), vw = lrelu((v.w - m) * r);
    mx = fmaxf(mx, fmaxf(fmaxf(vx, vy), fmaxf(vz, vw)));
    sm += vx + vy + vz + vw;
  }
#pragma unroll
  for (int s = 16; s > 0; s >>= 1) {
    mx = fmaxf(mx, __shfl_xor(mx, s));
    sm += __shfl_xor(sm, s);
  }
  if (l == 0) {
    p[b * 2048 + o] = mx;
    p[b * 2048 + 1024 + o] = sm * (1.f / NN);
  }
}

__global__ __launch_bounds__(64) void linear_kernel(const float* __restrict__ in, int IN, int OUT,
                                                    const float* __restrict__ w,
                                                    const float* __restrict__ bias,
                                                    float* __restrict__ out) {
  int o = blockIdx.x;
  int b = o / OUT, f = o % OUT;
  const float* ip = in + (size_t)b * IN;
  const float* wp = w + (size_t)f * IN;
  float a = 0.f;
  for (int i = threadIdx.x; i < IN; i += 64) a += ip[i] * wp[i];
#pragma unroll
  for (int s = 32; s > 0; s >>= 1) a += __shfl_down(a, s);
  if (threadIdx.x == 0) out[o] = a + bias[f];
}

__global__ __launch_bounds__(256) void bnf_kernel(float* __restrict__ t, int F) {
  int f = blockIdx.x * blockDim.x + threadIdx.x;
  if (f >= F) return;
  float s = 0.f, s2 = 0.f;
  for (int b = 0; b < BB; ++b) { float v = t[b * F + f]; s += v; s2 += v * v; }
  float m = s * (1.f / BB);
  float var = s2 * (1.f / BB) - m * m;
  float r = rsqrtf(var + 1e-5f);
  for (int b = 0; b < BB; ++b) {
    float v = (t[b * F + f] - m) * r;
    t[b * F + f] = v >= 0.f ? v : 0.2f * v;
  }
}

// ---------------------------------------------------------------- host side

struct SAW { const float *wq, *wk, *wv, *wc; };

static inline void run_conv(const float* in, int inBS, int C, int O, const float* w,
                            float* z, hipStream_t st) {
  if (O % 128 == 0)
    conv_gemm128_db_kernel<<<dim3(NN / 128, O / 128, BB), 256, 0, st>>>(in, inBS, C, O, w, z);
  else
    conv_gemm_kernel<false, false><<<dim3(NN / 64, (O + 63) / 64, BB), 256, 0, st>>>(in, inBS, C, O, w, z);
}

// C=64/128 path. Weights (M/WCV/Mb/wcvb) precomputed upfront.
template <int C, bool MFMA>
static inline void run_sa(const float* xin, int xbs,
                          float* xT, float* UT, float* AGGt, float* z, float* h,
                          float* sq, int* idx,
                          const float* M, const float* WCV,
                          const unsigned short* Mb, const unsigned short* wcvb,
                          unsigned short* xTb, unsigned short* AGGtb,
                          _Float16* xhi, _Float16* xlo,
                          float* D, int nbatch, hipStream_t st) {
  static_assert(C % 32 == 0, "run_sa requires C % 32 == 0");
  xprep_kernel<true, MFMA><<<dim3(NN / 32, C / 32, BB), 256, 0, st>>>(
      xin, xbs, C, xT, xhi, xlo, xTb, sq);
  for (int bb = 0; bb < BB; bb += nbatch) {
    int nbc = (BB - bb) < nbatch ? (BB - bb) : nbatch;
    pd_mfma_sym_kernel<<<dim3(136, nbc), 256, 0, st>>>(xhi, xlo, C, sq, D, bb);
    topk_bsort_kernel<<<dim3(NN / 4, nbc), 256, 0, st>>>(D, idx, bb);
  }
  if (MFMA) {
    mfma_gemm_lds_kernel<true, false><<<dim3(NN / 128, C / 128, BB), 256, 0, st>>>(
        (const unsigned short*)Mb, xTb, UT, C, C, nullptr);
    att_wave_reg_kernel<C, true><<<BB * NN / 4, 256, 0, st>>>(xT, UT, idx, nullptr, AGGtb);
    mfma_gemm_lds_kernel<false, false><<<dim3(NN / 128, C / 128, BB), 256, 0, st>>>(
        (const unsigned short*)wcvb, AGGtb, z, C, C, nullptr);
  } else {
    conv_gemm_kernel<false, true><<<dim3(NN / 64, C / 64, BB), 256, 0, st>>>(xin, xbs, C, C, M, UT);
    att_wave_reg_kernel<C, false><<<BB * NN / 4, 256, 0, st>>>(xT, UT, idx, AGGt, nullptr);
    conv_gemm_kernel<true, false><<<dim3(NN / 64, C / 64, BB), 256, 0, st>>>(AGGt, NN * C, C, C, WCV, z);
  }
  bn_copy_kernel<<<2 * C, 256, 0, st>>>(z, C, xin, xbs, h);
}

// SA1 (C=3): fused on-the-fly distances in topk_c3.
static inline void run_sa3(const float* xin,
                           float* xT, float* U, float* UT, float* AGGt, float* AGG,
                           float* z, float* h, float* xs4, int* idx,
                           const float* M, const float* WCV, hipStream_t st) {
  xprep3_kernel<<<dim3(NN / 256, 1, BB), 256, 0, st>>>(xin, xT, xs4);
  topk_c3_kernel<<<dim3(NN / 4, BB), 256, 0, st>>>(xs4, idx);
  conv_gemm_kernel<false, false><<<dim3(NN / 64, 1, BB), 256, 0, st>>>(xin, 3 * NN, 3, 3, M, U);
  transpose_kernel<<<dim3(NN / 32, 1, BB), 256, 0, st>>>(U, 3 * NN, 3, NN, UT);
  att_wave_kernel<3, false><<<BB * NN, 64, 0, st>>>(xT, UT, idx, AGGt, nullptr);
  transpose_kernel<<<dim3(1, NN / 32, BB), 256, 0, st>>>(AGGt, NN * 3, NN, 3, AGG);
  conv_gemm_kernel<false, false><<<dim3(NN / 64, 1, BB), 256, 0, st>>>(AGG, 3 * NN, 3, 3, WCV, z);
  bn_copy_kernel<<<6, 256, 0, st>>>(z, 3, xin, 3 * NN, h);
}

static inline void run_conv_bn(const float* in, int inBS, int Cin, int O, const float* w,
                               float* z, float* out, int outBS, int c0, hipStream_t st) {
  run_conv(in, inBS, Cin, O, w, z, st);
  bn_fused_kernel<false><<<O, 256, 0, st>>>(z, O, out, outBS, c0, nullptr);
}

extern "C" void kernel_launch(void* const* d_in, const int* in_sizes, int n_in,
                              void* d_out, int out_size, void* d_ws, size_t ws_size,
                              hipStream_t stream) {
  const float* x = (const float*)d_in[0];
  SAW sa1{(const float*)d_in[1], (const float*)d_in[2], (const float*)d_in[3], (const float*)d_in[4]};
  SAW sa2{(const float*)d_in[5], (const float*)d_in[6], (const float*)d_in[7], (const float*)d_in[8]};
  SAW sa3{(const float*)d_in[9], (const float*)d_in[10], (const float*)d_in[11], (const float*)d_in[12]};
  SAW sa4{(const float*)d_in[13], (const float*)d_in[14], (const float*)d_in[15], (const float*)d_in[16]};
  const float* conv1_w = (const float*)d_in[17];
  const float* conv2_w = (const float*)d_in[18];
  const float* conv3_w = (const float*)d_in[19];
  const float* conv4_w = (const float*)d_in[20];
  const float* conv5_w = (const float*)d_in[21];
  const float* lin1_w = (const float*)d_in[22];
  const float* lin1_b = (const float*)d_in[23];
  const float* lin2_w = (const float*)d_in[24];
  const float* lin2_b = (const float*)d_in[25];
  const float* lin3_w = (const float*)d_in[26];
  const float* lin3_b = (const float*)d_in[27];

  char* ws = (char*)d_ws;
  size_t off = 0;
  auto take = [&](size_t bytes) -> void* {
    void* p = ws + off;
    off += (bytes + 255) & ~(size_t)255;
    return p;
  };
  float* sqR  = (float*)take((size_t)3 * BB * NN * 4);       // SA2/3/4 sq, zeroed once
  float* statsR = (float*)take((size_t)(256 + 1024) * 2 * 4); // conv4+conv5 BN stats (contig w/ sqR)
  float* xs4  = (float*)take((size_t)BB * NN * 4 * 4);       // SA1 {x,y,z,sq}
  int*   idx  = (int*)take((size_t)BB * NN * KNB * 4);
  float* Mall = (float*)take((size_t)4 * 128 * 128 * 4);     // per-SA M
  float* Wall = (float*)take((size_t)4 * 128 * 128 * 4);     // per-SA WCV
  unsigned short* Mb4   = (unsigned short*)take((size_t)128 * 128 * 2);
  unsigned short* wcvb4 = (unsigned short*)take((size_t)128 * 128 * 2);
  unsigned short* w4b  = (unsigned short*)take((size_t)256 * 256 * 2);
  unsigned short* w5b  = (unsigned short*)take((size_t)1024 * 512 * 2);
  float* U    = (float*)take((size_t)BB * 128 * NN * 4);  // SA1 U / conv4-5 bf16 overlays
  float* AGG  = (float*)take((size_t)BB * 128 * NN * 4);  // hosts xT (+ AGGt for SA2/3)
  float* h    = (float*)take((size_t)BB * 256 * NN * 4);  // overlays below
  float* z    = (float*)take((size_t)BB * 1024 * NN * 4); // hosts AGGtb(+16MB), D-chunks
  float* xc   = (float*)take((size_t)BB * 512 * NN * 4);
  float* p    = (float*)take((size_t)BB * 2048 * 4);
  float* t1   = (float*)take((size_t)BB * 512 * 4);
  float* t2   = (float*)take((size_t)BB * 256 * 4);
  (void)n_in; (void)in_sizes; (void)out_size;

  float* M1 = Mall + 0 * 16384; float* W1 = Wall + 0 * 16384;
  float* M2 = Mall + 1 * 16384; float* W2 = Wall + 1 * 16384;
  float* M3 = Mall + 2 * 16384; float* W3 = Wall + 2 * 16384;
  float* M4 = Mall + 3 * 16384; float* W4 = Wall + 3 * 16384;
  float* stats4 = statsR;            // 256 ch
  float* stats5 = statsR + 256 * 2;  // 1024 ch

  // Overlays (phase-ordered lifetimes):
  float* xT = AGG;                                          // first half of AGG (C<=128)
  float* AGGt64 = AGG + (size_t)BB * NN * 64;               // SA2/3 AGGt [n][64] (2nd half of AGG)
  float* UT = h;                                            // consumed before h written
  float* AGGt1 = z;                                         // SA1 AGGt (z scratch)
  unsigned short* xTb   = (unsigned short*)((char*)h + (size_t)BB * 128 * NN * 4);  // h 2nd half
  unsigned short* AGGtb = (unsigned short*)((char*)z + (size_t)16 * 1024 * 1024);   // z + 16 MB
  unsigned short* hTb   = (unsigned short*)U;               // conv4 phase (U dead)
  unsigned short* xcTb  = (unsigned short*)U;               // conv5 phase (U dead, 16.8 MB)
  _Float16* xhi = (_Float16*)h;                             // pd phase only (UT written after)
  _Float16* xlo = (_Float16*)((char*)h + (size_t)BB * NN * 128 * 2);

  size_t dfull = (size_t)BB * NN * NN * 4;
  bool fullD = (ws_size > off + dfull + 4096);
  float* D = fullD ? (float*)take(dfull) : z;               // !fullD: 4-batch chunks fill z exactly
  int nbatch = fullD ? BB : 4;

  // One upfront zero for sq regions + BN stats (contiguous takes).
  hipMemsetAsync(sqR, 0, (size_t)3 * BB * NN * 4 + (size_t)(256 + 1024) * 2 * 4, stream);
  // All weight-derived tensors in one launch (no activation deps).
  weight_prep_kernel<<<5 + 2048 + 2048 + 8192 + 256 + 2048, 256, 0, stream>>>(
      sa1.wq, sa1.wk, sa1.wv, sa1.wc, sa2.wq, sa2.wk, sa2.wv, sa2.wc,
      sa3.wq, sa3.wk, sa3.wv, sa3.wc, sa4.wq, sa4.wk, sa4.wv, sa4.wc,
      conv4_w, conv5_w, M1, W1, M2, W2, M3, W3, M4, W4, Mb4, wcvb4, w4b, w5b);

  // SA1 (C=3) -> h [B,6,N]
  run_sa3(x, xT, U, UT, AGGt1, AGG, z, h, xs4, idx, M1, W1, stream);
  run_conv_bn(h, 6 * NN, 6, 64, conv1_w, z, xc, 512 * NN, 0, stream);
  // SA2 (C=64) on x1
  run_sa<64, false>(xc + 0 * NN, 512 * NN, xT, UT, AGGt64, z, h,
                    sqR + 0 * BB * NN, idx, M2, W2, nullptr, nullptr, xTb, AGGtb, xhi, xlo,
                    D, nbatch, stream);
  run_conv_bn(h, 128 * NN, 128, 64, conv2_w, z, xc, 512 * NN, 64, stream);
  // SA3 (C=64) on x2
  run_sa<64, false>(xc + 64 * NN, 512 * NN, xT, UT, AGGt64, z, h,
                    sqR + 1 * BB * NN, idx, M3, W3, nullptr, nullptr, xTb, AGGtb, xhi, xlo,
                    D, nbatch, stream);
  run_conv_bn(h, 128 * NN, 128, 128, conv3_w, z, xc, 512 * NN, 128, stream);
  // SA4 (C=128) on x3 — bf16 MFMA for U and Z convs
  run_sa<128, true>(xc + 128 * NN, 512 * NN, xT, UT, nullptr, z, h,
                    sqR + 2 * BB * NN, idx, M4, W4, Mb4, wcvb4, xTb, AGGtb, xhi, xlo,
                    D, nbatch, stream);
  // conv4 (bf16 MFMA + fused BN stats): h [B,256,N] -> z [B,256,N]
  transpose_bf16_kernel<<<dim3(NN / 32, 8, BB), 256, 0, stream>>>(h, 256 * NN, 256, NN, hTb);
  mfma_gemm_lds_kernel<false, true><<<dim3(NN / 128, 2, BB), 256, 0, stream>>>(
      w4b, hTb, z, 256, 256, stats4);
  bn_fused_kernel<true><<<256, 256, 0, stream>>>(z, 256, xc, 512 * NN, 256, stats4);
  // conv5 (bf16 MFMA + fused BN stats): xc [B,512,N] -> z [B,1024,N]; BN+LReLU+pool -> p
  transpose_bf16_kernel<<<dim3(NN / 32, 16, BB), 256, 0, stream>>>(xc, 512 * NN, 512, NN, xcTb);
  mfma_gemm_lds_kernel<false, true><<<dim3(NN / 128, 8, BB), 256, 0, stream>>>(
      w5b, xcTb, z, 1024, 512, stats5);
  bn_pool_kernel<true><<<1024, 256, 0, stream>>>(z, p, stats5);
  // FC head
  linear_kernel<<<BB * 512, 64, 0, stream>>>(p, 2048, 512, lin1_w, lin1_b, t1);
  bnf_kernel<<<2, 256, 0, stream>>>(t1, 512);
  linear_kernel<<<BB * 256, 64, 0, stream>>>(t1, 512, 256, lin2_w, lin2_b, t2);
  bnf_kernel<<<1, 256, 0, stream>>>(t2, 256);
  linear_kernel<<<BB * 40, 64, 0, stream>>>(t2, 256, 40, lin3_w, lin3_b, (float*)d_out);
}

// Round 5
// 828.621 us; speedup vs baseline: 1.0459x; 1.0459x over previous
//
#include <hip/hip_runtime.h>
#include <math.h>

#define BB 8
#define NN 2048
#define KNB 20

typedef __attribute__((ext_vector_type(8))) short bf16x8;
typedef __attribute__((ext_vector_type(8))) _Float16 f16x8;
typedef __attribute__((ext_vector_type(4))) float f32x4;

__device__ inline unsigned short f2bf(float f) {
  union { float f; unsigned u; } v; v.f = f;
  unsigned r = v.u + 0x7FFF + ((v.u >> 16) & 1);  // RNE
  return (unsigned short)(r >> 16);
}

__device__ inline float lrelu(float v) { return v >= 0.f ? v : 0.2f * v; }

// ---------------------------------------------------------------- fused x-prep
template <bool F16SPLIT, bool BF16>
__global__ __launch_bounds__(256) void xprep_kernel(
    const float* __restrict__ in, int inBS, int C,
    float* __restrict__ xT, _Float16* __restrict__ hi, _Float16* __restrict__ lo,
    unsigned short* __restrict__ bf, float* __restrict__ sq) {
  __shared__ float tile[32][33];
  __shared__ float ps[8][33];
  int b = blockIdx.z;
  const float* ip = in + (size_t)b * inBS;
  int c0 = blockIdx.x * 32;   // point index n
  int r0 = blockIdx.y * 32;   // channel index
  int tx = threadIdx.x & 31, ty = threadIdx.x >> 5;
  float s = 0.f;
  for (int yy = ty; yy < 32; yy += 8) {
    int r = r0 + yy;
    float v = (r < C) ? ip[(size_t)r * NN + c0 + tx] : 0.f;
    tile[yy][tx] = v;
    s += v * v;
  }
  ps[ty][tx] = s;
  __syncthreads();
  if (ty == 0) {
    float a = ps[0][tx];
#pragma unroll
    for (int u = 1; u < 8; ++u) a += ps[u][tx];
    atomicAdd(&sq[b * NN + c0 + tx], a);
  }
  for (int yy = ty; yy < 32; yy += 8) {
    int c = c0 + yy, r = r0 + tx;   // c = n, r = channel
    if (r < C) {
      float v = tile[tx][yy];
      size_t o = (size_t)b * NN * C + (size_t)c * C + r;
      xT[o] = v;
      if (F16SPLIT) {
        _Float16 hv = (_Float16)v;
        hi[o] = hv;
        lo[o] = (_Float16)(v - (float)hv);
      }
      if (BF16) bf[o] = f2bf(v);
    }
  }
}

// ---------------------------------------------------------------- SA1 (C=3) prep
__global__ __launch_bounds__(256) void xprep3_kernel(const float* __restrict__ in,
                                                     float* __restrict__ xs4) {
  int b = blockIdx.z;
  int n = blockIdx.x * 256 + threadIdx.x;
  const float* ip = in + (size_t)b * 3 * NN;
  float x0 = ip[n], x1 = ip[NN + n], x2 = ip[2 * NN + n];
  float s = x0 * x0 + x1 * x1 + x2 * x2;
  size_t o = (size_t)b * NN + n;
  *(float4*)&xs4[o * 4] = make_float4(x0, x1, x2, s);
}

// ---------------------------------------------------------------- weight prep (all SAs + conv4/5 converts, one launch)
__device__ inline void mw_task(const float* __restrict__ wq, const float* __restrict__ wk,
                               const float* __restrict__ wv, const float* __restrict__ wc,
                               int C, float* __restrict__ M, float* __restrict__ WCV,
                               unsigned short* __restrict__ Mb, unsigned short* __restrict__ wcvb,
                               bool emitBF, int w, int lane) {
  int total = 2 * C * C;
  if (w >= total) return;
  float a = 0.f;
  if (w < C * C) {
    int c = w / C, cp = w - c * C;
    for (int e = lane; e < C; e += 64) a += wk[e * C + c] * wq[e * C + cp];
  } else {
    int t = w - C * C;
    int o = t / C, c = t - o * C;
    for (int e = lane; e < C; e += 64) a += wc[o * C + e] * wv[e * C + c];
  }
#pragma unroll
  for (int s = 32; s > 0; s >>= 1) a += __shfl_down(a, s);
  if (lane == 0) {
    if (w < C * C) {
      M[w] = a;
      if (emitBF) Mb[w] = f2bf(a);
    } else {
      int t = w - C * C;
      WCV[t] = a;
      if (emitBF) wcvb[t] = f2bf(a);
    }
  }
}

__global__ __launch_bounds__(256) void weight_prep_kernel(
    const float* wq1, const float* wk1, const float* wv1, const float* wc1,
    const float* wq2, const float* wk2, const float* wv2, const float* wc2,
    const float* wq3, const float* wk3, const float* wv3, const float* wc3,
    const float* wq4, const float* wk4, const float* wv4, const float* wc4,
    const float* conv4_w, const float* conv5_w,
    float* M1, float* W1, float* M2, float* W2, float* M3, float* W3, float* M4, float* W4,
    unsigned short* Mb4, unsigned short* wcvb4,
    unsigned short* w4b, unsigned short* w5b) {
  int bx = blockIdx.x;
  int lane = threadIdx.x & 63;
  int wv_ = threadIdx.x >> 6;
  if (bx < 5) {                       // SA1: 2*3*3 = 18 tasks
    mw_task(wq1, wk1, wv1, wc1, 3, M1, W1, nullptr, nullptr, false, bx * 4 + wv_, lane);
    return;
  }
  bx -= 5;
  if (bx < 2048) {                    // SA2: 2*64*64 tasks
    mw_task(wq2, wk2, wv2, wc2, 64, M2, W2, nullptr, nullptr, false, bx * 4 + wv_, lane);
    return;
  }
  bx -= 2048;
  if (bx < 2048) {                    // SA3
    mw_task(wq3, wk3, wv3, wc3, 64, M3, W3, nullptr, nullptr, false, bx * 4 + wv_, lane);
    return;
  }
  bx -= 2048;
  if (bx < 8192) {                    // SA4: 2*128*128 tasks, emit bf16
    mw_task(wq4, wk4, wv4, wc4, 128, M4, W4, Mb4, wcvb4, true, bx * 4 + wv_, lane);
    return;
  }
  bx -= 8192;
  if (bx < 256) {                     // conv4 weight convert
    int i = bx * 256 + threadIdx.x;
    w4b[i] = f2bf(conv4_w[i]);
    return;
  }
  bx -= 256;
  {                                   // conv5 weight convert (2048 blocks)
    int i = bx * 256 + threadIdx.x;
    w5b[i] = f2bf(conv5_w[i]);
  }
}

// ---------------------------------------------------------------- transpose + bf16 convert
__global__ __launch_bounds__(256) void transpose_bf16_kernel(const float* __restrict__ in, int inBS,
                                                             int R, int Cl,
                                                             unsigned short* __restrict__ out) {
  __shared__ float tile[32][33];
  int b = blockIdx.z;
  const float* ip = in + (size_t)b * inBS;
  unsigned short* op = out + (size_t)b * R * Cl;
  int c0 = blockIdx.x * 32, r0 = blockIdx.y * 32;
  int tx = threadIdx.x & 31, ty = threadIdx.x >> 5;
  for (int yy = ty; yy < 32; yy += 8) {
    int r = r0 + yy, c = c0 + tx;
    tile[yy][tx] = (r < R && c < Cl) ? ip[(size_t)r * Cl + c] : 0.f;
  }
  __syncthreads();
  for (int yy = ty; yy < 32; yy += 8) {
    int c = c0 + yy, r = r0 + tx;
    if (c < Cl && r < R) op[(size_t)c * R + r] = f2bf(tile[tx][yy]);
  }
}

// ---------------------------------------------------------------- MFMA GEMM 128x128, VGPR-staged dbuf (R3 schedule)
// TOUT: write output transposed as Z[n][o]. STATS: per-channel sum/sumsq.
template <bool TOUT, bool STATS>
__global__ __launch_bounds__(256, 2) void mfma_gemm_lds_kernel(
    const unsigned short* __restrict__ A, const unsigned short* __restrict__ B,
    float* __restrict__ Z, int O, int K, float* __restrict__ gstats) {
  const int b = blockIdx.z;
  const int n0 = blockIdx.x * 128, o0 = blockIdx.y * 128;
  const int tid = threadIdx.x;
  const int wave = tid >> 6, lane = tid & 63;
  const int wo = wave >> 1, wn = wave & 1;
  const int l16 = lane & 15, q = lane >> 4;
  __shared__ unsigned short Al[2][4096];
  __shared__ unsigned short Bl[2][4096];
  const unsigned short* Ab = A + (size_t)o0 * K;
  const unsigned short* Bb = B + ((size_t)b * NN + n0) * K;

  const int p0 = tid, p1 = tid + 256;
  const int r0 = ((p0 >> 6) << 4) | (p0 & 15), c0 = ((p0 >> 4) & 3) * 8;
  const int r1 = ((p1 >> 6) << 4) | (p1 & 15), c1 = ((p1 >> 4) & 3) * 8;

  bf16x8 ar0, ar1, br0, br1;
  auto gload = [&](int k0) {
    ar0 = *(const bf16x8*)(Ab + (size_t)r0 * K + k0 + c0);
    ar1 = *(const bf16x8*)(Ab + (size_t)r1 * K + k0 + c1);
    br0 = *(const bf16x8*)(Bb + (size_t)r0 * K + k0 + c0);
    br1 = *(const bf16x8*)(Bb + (size_t)r1 * K + k0 + c1);
  };
  auto sstore = [&](int buf) {
    *(bf16x8*)&Al[buf][p0 * 8] = ar0;
    *(bf16x8*)&Al[buf][p1 * 8] = ar1;
    *(bf16x8*)&Bl[buf][p0 * 8] = br0;
    *(bf16x8*)&Bl[buf][p1 * 8] = br1;
  };

  f32x4 acc[4][4];
#pragma unroll
  for (int s = 0; s < 4; ++s)
#pragma unroll
    for (int t = 0; t < 4; ++t) acc[s][t] = (f32x4){0.f, 0.f, 0.f, 0.f};

  gload(0);
  sstore(0);
  int cur = 0;
  for (int k0 = 0; k0 < K; k0 += 32) {
    bool more = (k0 + 32) < K;
    if (more) gload(k0 + 32);
    __syncthreads();
    bf16x8 af[4], bfr[4];
#pragma unroll
    for (int s = 0; s < 4; ++s)
      af[s] = *(const bf16x8*)&Al[cur][((wo * 4 + s) * 64 + q * 16 + l16) * 8];
#pragma unroll
    for (int t = 0; t < 4; ++t)
      bfr[t] = *(const bf16x8*)&Bl[cur][((wn * 4 + t) * 64 + q * 16 + l16) * 8];
#pragma unroll
    for (int s = 0; s < 4; ++s)
#pragma unroll
      for (int t = 0; t < 4; ++t)
        acc[s][t] = __builtin_amdgcn_mfma_f32_16x16x32_bf16(af[s], bfr[t], acc[s][t], 0, 0, 0);
    if (more) sstore(cur ^ 1);
    cur ^= 1;
  }
#pragma unroll
  for (int s = 0; s < 4; ++s)
#pragma unroll
    for (int t = 0; t < 4; ++t) {
      if (TOUT) {
        int n = n0 + wn * 64 + t * 16 + l16;
        int ob = o0 + wo * 64 + s * 16 + q * 4;
        *(f32x4*)&Z[((size_t)b * NN + n) * O + ob] = acc[s][t];
      } else {
        float* zp = Z + ((size_t)b * O + o0 + wo * 64 + s * 16 + q * 4) * NN
                    + n0 + wn * 64 + t * 16 + l16;
#pragma unroll
        for (int r = 0; r < 4; ++r) zp[(size_t)r * NN] = acc[s][t][r];
      }
    }
  if (STATS) {
    float psum[16], psq[16];
#pragma unroll
    for (int s = 0; s < 4; ++s)
#pragma unroll
      for (int r = 0; r < 4; ++r) {
        float a = 0.f, sa = 0.f;
#pragma unroll
        for (int t = 0; t < 4; ++t) { float v = acc[s][t][r]; a += v; sa += v * v; }
        psum[s * 4 + r] = a; psq[s * 4 + r] = sa;
      }
#pragma unroll
    for (int i = 0; i < 16; ++i) {
#pragma unroll
      for (int mm = 1; mm < 16; mm <<= 1) {
        psum[i] += __shfl_xor(psum[i], mm);
        psq[i] += __shfl_xor(psq[i], mm);
      }
    }
    __syncthreads();                 // staging LDS no longer needed
    float* sb = (float*)&Al[0][0];   // 128 ch x {sum,sq}
    sb[tid] = 0.f;
    __syncthreads();
    if (l16 == 0) {
#pragma unroll
      for (int i = 0; i < 16; ++i) {
        int ch = wo * 64 + (i >> 2) * 16 + q * 4 + (i & 3);
        atomicAdd(&sb[ch * 2], psum[i]);
        atomicAdd(&sb[ch * 2 + 1], psq[i]);
      }
    }
    __syncthreads();
    atomicAdd(&gstats[o0 * 2 + tid], sb[tid]);
  }
}

// ---------------------------------------------------------------- MFMA GEMM 256(n)x128(o), VGPR-staged dbuf
// 32 MFMA per barrier (vs 16 in the 128-tile) -> better MFMA:stall ratio for
// the big conv5 GEMM. Always STATS epilogue.
__global__ __launch_bounds__(256, 2) void mfma_gemm_n256_kernel(
    const unsigned short* __restrict__ A, const unsigned short* __restrict__ B,
    float* __restrict__ Z, int O, int K, float* __restrict__ gstats) {
  const int b = blockIdx.z;
  const int n0 = blockIdx.x * 256, o0 = blockIdx.y * 128;
  const int tid = threadIdx.x;
  const int wave = tid >> 6, lane = tid & 63;
  const int wo = wave >> 1, wn = wave & 1;
  const int l16 = lane & 15, q = lane >> 4;
  __shared__ unsigned short Al[2][4096];   // 128 o x 32 k
  __shared__ unsigned short Bl[2][8192];   // 256 n x 32 k
  const unsigned short* Ab = A + (size_t)o0 * K;
  const unsigned short* Bb = B + ((size_t)b * NN + n0) * K;

  const int pA0 = tid, pA1 = tid + 256;
  const int rA0 = ((pA0 >> 6) << 4) | (pA0 & 15), cA0 = ((pA0 >> 4) & 3) * 8;
  const int rA1 = ((pA1 >> 6) << 4) | (pA1 & 15), cA1 = ((pA1 >> 4) & 3) * 8;

  bf16x8 ar0, ar1, br[4];
  auto gload = [&](int k0) {
    ar0 = *(const bf16x8*)(Ab + (size_t)rA0 * K + k0 + cA0);
    ar1 = *(const bf16x8*)(Ab + (size_t)rA1 * K + k0 + cA1);
#pragma unroll
    for (int i = 0; i < 4; ++i) {
      int p = tid + 256 * i;
      int r = ((p >> 6) << 4) | (p & 15), c = ((p >> 4) & 3) * 8;
      br[i] = *(const bf16x8*)(Bb + (size_t)r * K + k0 + c);
    }
  };
  auto sstore = [&](int buf) {
    *(bf16x8*)&Al[buf][pA0 * 8] = ar0;
    *(bf16x8*)&Al[buf][pA1 * 8] = ar1;
#pragma unroll
    for (int i = 0; i < 4; ++i) *(bf16x8*)&Bl[buf][(tid + 256 * i) * 8] = br[i];
  };

  f32x4 acc[4][8];   // [o-frag s][n-frag t]
#pragma unroll
  for (int s = 0; s < 4; ++s)
#pragma unroll
    for (int t = 0; t < 8; ++t) acc[s][t] = (f32x4){0.f, 0.f, 0.f, 0.f};

  gload(0);
  sstore(0);
  int cur = 0;
  for (int k0 = 0; k0 < K; k0 += 32) {
    bool more = (k0 + 32) < K;
    if (more) gload(k0 + 32);
    __syncthreads();
    bf16x8 af[4], bfr[8];
#pragma unroll
    for (int s = 0; s < 4; ++s)
      af[s] = *(const bf16x8*)&Al[cur][((wo * 4 + s) * 64 + q * 16 + l16) * 8];
#pragma unroll
    for (int t = 0; t < 8; ++t)
      bfr[t] = *(const bf16x8*)&Bl[cur][((wn * 8 + t) * 64 + q * 16 + l16) * 8];
#pragma unroll
    for (int s = 0; s < 4; ++s)
#pragma unroll
      for (int t = 0; t < 8; ++t)
        acc[s][t] = __builtin_amdgcn_mfma_f32_16x16x32_bf16(af[s], bfr[t], acc[s][t], 0, 0, 0);
    if (more) sstore(cur ^ 1);
    cur ^= 1;
  }
#pragma unroll
  for (int s = 0; s < 4; ++s)
#pragma unroll
    for (int t = 0; t < 8; ++t) {
      float* zp = Z + ((size_t)b * O + o0 + wo * 64 + s * 16 + q * 4) * NN
                  + n0 + wn * 128 + t * 16 + l16;
#pragma unroll
      for (int r = 0; r < 4; ++r) zp[(size_t)r * NN] = acc[s][t][r];
    }
  {  // stats
    float psum[16], psq[16];
#pragma unroll
    for (int s = 0; s < 4; ++s)
#pragma unroll
      for (int r = 0; r < 4; ++r) {
        float a = 0.f, sa = 0.f;
#pragma unroll
        for (int t = 0; t < 8; ++t) { float v = acc[s][t][r]; a += v; sa += v * v; }
        psum[s * 4 + r] = a; psq[s * 4 + r] = sa;
      }
#pragma unroll
    for (int i = 0; i < 16; ++i) {
#pragma unroll
      for (int mm = 1; mm < 16; mm <<= 1) {
        psum[i] += __shfl_xor(psum[i], mm);
        psq[i] += __shfl_xor(psq[i], mm);
      }
    }
    __syncthreads();
    float* sb = (float*)&Al[0][0];   // 128 ch x {sum,sq}
    sb[tid] = 0.f;
    __syncthreads();
    if (l16 == 0) {
#pragma unroll
      for (int i = 0; i < 16; ++i) {
        int ch = wo * 64 + (i >> 2) * 16 + q * 4 + (i & 3);
        atomicAdd(&sb[ch * 2], psum[i]);
        atomicAdd(&sb[ch * 2 + 1], psq[i]);
      }
    }
    __syncthreads();
    atomicAdd(&gstats[o0 * 2 + tid], sb[tid]);
  }
}

// ---------------------------------------------------------------- pd via f16 split MFMA, symmetric tiles (R3 staging)
__global__ __launch_bounds__(256, 2) void pd_mfma_sym_kernel(
    const _Float16* __restrict__ xhi, const _Float16* __restrict__ xlo, int C,
    const float* __restrict__ sq, float* __restrict__ P, int b_base) {
  const int bl = blockIdx.y;
  const int b = b_base + bl;
  int ti = 0, xx = blockIdx.x;
  while (xx >= 16 - ti) { xx -= 16 - ti; ++ti; }
  const int tj = ti + xx;
  const int n0 = ti * 128, m0 = tj * 128;
  const int tid = threadIdx.x;
  const int wave = tid >> 6, lane = tid & 63;
  const int wn_ = wave >> 1, wm_ = wave & 1;
  const int l16 = lane & 15, q = lane >> 4;
  __shared__ _Float16 Ah[4096], Al[4096], Bh[4096], Bl[4096];
  const _Float16* Ahg = xhi + ((size_t)b * NN + n0) * C;
  const _Float16* Alg = xlo + ((size_t)b * NN + n0) * C;
  const _Float16* Bhg = xhi + ((size_t)b * NN + m0) * C;
  const _Float16* Blg = xlo + ((size_t)b * NN + m0) * C;

  const int p0 = tid, p1 = tid + 256;
  const int r0 = ((p0 >> 6) << 4) | (p0 & 15), c0 = ((p0 >> 4) & 3) * 8;
  const int r1 = ((p1 >> 6) << 4) | (p1 & 15), c1 = ((p1 >> 4) & 3) * 8;

  f32x4 acc[4][4];
#pragma unroll
  for (int s = 0; s < 4; ++s)
#pragma unroll
    for (int t = 0; t < 4; ++t) acc[s][t] = (f32x4){0.f, 0.f, 0.f, 0.f};

  for (int k0 = 0; k0 < C; k0 += 32) {
    __syncthreads();
    *(f16x8*)&Ah[p0 * 8] = *(const f16x8*)(Ahg + (size_t)r0 * C + k0 + c0);
    *(f16x8*)&Ah[p1 * 8] = *(const f16x8*)(Ahg + (size_t)r1 * C + k0 + c1);
    *(f16x8*)&Al[p0 * 8] = *(const f16x8*)(Alg + (size_t)r0 * C + k0 + c0);
    *(f16x8*)&Al[p1 * 8] = *(const f16x8*)(Alg + (size_t)r1 * C + k0 + c1);
    *(f16x8*)&Bh[p0 * 8] = *(const f16x8*)(Bhg + (size_t)r0 * C + k0 + c0);
    *(f16x8*)&Bh[p1 * 8] = *(const f16x8*)(Bhg + (size_t)r1 * C + k0 + c1);
    *(f16x8*)&Bl[p0 * 8] = *(const f16x8*)(Blg + (size_t)r0 * C + k0 + c0);
    *(f16x8*)&Bl[p1 * 8] = *(const f16x8*)(Blg + (size_t)r1 * C + k0 + c1);
    __syncthreads();
    f16x8 ah[4], al[4], bh[4], blv[4];
#pragma unroll
    for (int s = 0; s < 4; ++s) {
      int pi = ((wn_ * 4 + s) * 64 + q * 16 + l16) * 8;
      ah[s] = *(const f16x8*)&Ah[pi];
      al[s] = *(const f16x8*)&Al[pi];
    }
#pragma unroll
    for (int t = 0; t < 4; ++t) {
      int pi = ((wm_ * 4 + t) * 64 + q * 16 + l16) * 8;
      bh[t] = *(const f16x8*)&Bh[pi];
      blv[t] = *(const f16x8*)&Bl[pi];
    }
#pragma unroll
    for (int s = 0; s < 4; ++s)
#pragma unroll
      for (int t = 0; t < 4; ++t) {
        acc[s][t] = __builtin_amdgcn_mfma_f32_16x16x32_f16(ah[s], bh[t], acc[s][t], 0, 0, 0);
        acc[s][t] = __builtin_amdgcn_mfma_f32_16x16x32_f16(ah[s], blv[t], acc[s][t], 0, 0, 0);
        acc[s][t] = __builtin_amdgcn_mfma_f32_16x16x32_f16(al[s], bh[t], acc[s][t], 0, 0, 0);
      }
  }
  // normal tile: rows in i-block, cols in j-block, minus sq[col]
#pragma unroll
  for (int s = 0; s < 4; ++s)
#pragma unroll
    for (int t = 0; t < 4; ++t) {
      int col = m0 + wm_ * 64 + t * 16 + l16;
      float sqv = sq[b * NN + col];
      float* pp = P + ((size_t)bl * NN + n0 + wn_ * 64 + s * 16 + q * 4) * NN + col;
#pragma unroll
      for (int r = 0; r < 4; ++r) pp[(size_t)r * NN] = 2.f * acc[s][t][r] - sqv;
    }
  // mirrored tile: rows in j-block, cols in i-block, minus sq[col=n]
  if (ti != tj) {
#pragma unroll
    for (int s = 0; s < 4; ++s) {
      int nb = n0 + wn_ * 64 + s * 16 + q * 4;
      float4 sqn = *(const float4*)&sq[b * NN + nb];
#pragma unroll
      for (int t = 0; t < 4; ++t) {
        int m = m0 + wm_ * 64 + t * 16 + l16;
        f32x4 ov;
        ov[0] = 2.f * acc[s][t][0] - sqn.x;
        ov[1] = 2.f * acc[s][t][1] - sqn.y;
        ov[2] = 2.f * acc[s][t][2] - sqn.z;
        ov[3] = 2.f * acc[s][t][3] - sqn.w;
        *(f32x4*)&P[((size_t)bl * NN + m) * NN + nb] = ov;
      }
    }
  }
}

// ---------------------------------------------------------------- top-20: slot-packed u32 bitonic
__global__ __launch_bounds__(256) void topk_bsort_kernel(const float* __restrict__ P,
                                                         int* __restrict__ idx_out, int b_base) {
  const int wave = threadIdx.x >> 6;
  const int lane = threadIdx.x & 63;
  const int n = blockIdx.x * 4 + wave;
  const int bl = blockIdx.y;
  const int b = b_base + bl;
  const float4* rp = (const float4*)(P + ((size_t)bl * NN + n) * NN);
  unsigned key[32];
#pragma unroll
  for (int q = 0; q < 8; ++q) {
    float4 vv = rp[q * 64 + lane];
    int mb = q * 256 + lane * 4;
    float fv[4] = {vv.x, vv.y, vv.z, vv.w};
#pragma unroll
    for (int j = 0; j < 4; ++j) {
      unsigned u = __float_as_uint(fv[j]);
      unsigned mask = (unsigned)(((int)u) >> 31) | 0x80000000u;
      unsigned sl = (unsigned)(q * 4 + j);
      key[q * 4 + j] = (mb + j == n) ? sl : (((u ^ mask) & 0xFFFFFFE0u) | sl);
    }
  }
#pragma unroll
  for (int k = 2; k <= 32; k <<= 1) {
#pragma unroll
    for (int j = k >> 1; j > 0; j >>= 1) {
#pragma unroll
      for (int i = 0; i < 32; ++i) {
        int l = i ^ j;
        if (l > i) {
          unsigned ka = key[i], kb = key[l];
          unsigned mx = ka > kb ? ka : kb;
          unsigned mn = ka > kb ? kb : ka;
          if ((i & k) == 0) { key[i] = mx; key[l] = mn; }
          else              { key[i] = mn; key[l] = mx; }
        }
      }
    }
  }
  int* op = idx_out + (size_t)(b * NN + n) * KNB;
  for (int k = 0; k < KNB; ++k) {
    unsigned best = key[0];
#pragma unroll
    for (int s = 32; s > 0; s >>= 1) {
      unsigned o = (unsigned)__shfl_xor((int)best, s);
      best = best > o ? best : o;
    }
    unsigned long long bal = __ballot(key[0] == best);
    if (lane == (int)__ffsll(bal) - 1) {
      unsigned sl = key[0] & 31u;
      op[k] = (int)((sl >> 2) * 256u + (unsigned)lane * 4u + (sl & 3u));
#pragma unroll
      for (int j = 0; j < 20; ++j) key[j] = key[j + 1];
    }
  }
}

// ---------------------------------------------------------------- SA1 fused distance + top-20 (C=3)
__global__ __launch_bounds__(256) void topk_c3_kernel(const float* __restrict__ xs4,
                                                      int* __restrict__ idx_out) {
  const int wave = threadIdx.x >> 6;
  const int lane = threadIdx.x & 63;
  const int n = blockIdx.x * 4 + wave;
  const int b = blockIdx.y;
  const float4* xp = (const float4*)(xs4 + (size_t)b * NN * 4);
  float4 me = xp[n];
  float tx = 2.f * me.x, ty = 2.f * me.y, tz = 2.f * me.z;
  unsigned key[32];
#pragma unroll
  for (int s = 0; s < 32; ++s) {
    int m = s * 64 + lane;
    float4 c = xp[m];
    float pd = tx * c.x + ty * c.y + tz * c.z - c.w;
    unsigned u = __float_as_uint(pd);
    unsigned mask = (unsigned)(((int)u) >> 31) | 0x80000000u;
    key[s] = (m == n) ? (unsigned)s : ((((u ^ mask) & 0xFFFFFFE0u)) | (unsigned)s);
  }
#pragma unroll
  for (int k = 2; k <= 32; k <<= 1) {
#pragma unroll
    for (int j = k >> 1; j > 0; j >>= 1) {
#pragma unroll
      for (int i = 0; i < 32; ++i) {
        int l = i ^ j;
        if (l > i) {
          unsigned ka = key[i], kb = key[l];
          unsigned mx = ka > kb ? ka : kb;
          unsigned mn = ka > kb ? kb : ka;
          if ((i & k) == 0) { key[i] = mx; key[l] = mn; }
          else              { key[i] = mn; key[l] = mx; }
        }
      }
    }
  }
  int* op = idx_out + (size_t)(b * NN + n) * KNB;
  for (int k = 0; k < KNB; ++k) {
    unsigned best = key[0];
#pragma unroll
    for (int s = 32; s > 0; s >>= 1) {
      unsigned o = (unsigned)__shfl_xor((int)best, s);
      best = best > o ? best : o;
    }
    unsigned long long bal = __ballot(key[0] == best);
    if (lane == (int)__ffsll(bal) - 1) {
      unsigned sl = key[0] & 31u;
      op[k] = (int)(sl * 64u + (unsigned)lane);
#pragma unroll
      for (int j = 0; j < 20; ++j) key[j] = key[j + 1];
    }
  }
}

// ---------------------------------------------------------------- SA1 fused U+att+Z (C=3), thread per point
// u = M(3x3).x; scores vs 20 gathered neighbors (xs4 L2-resident); softmax;
// agg = sum p_k nb_k - x; z = WCV(3x3).agg written [B,3,N]. Replaces
// conv(U) + transpose + att_wave + transpose + conv(Z).
__global__ __launch_bounds__(256) void sa1_fused_kernel(
    const float* __restrict__ xs4, const int* __restrict__ idx,
    const float* __restrict__ M, const float* __restrict__ W,
    float* __restrict__ z) {
  __shared__ float Ms[9], Ws9[9];
  int t = threadIdx.x;
  if (t < 9) Ms[t] = M[t];
  else if (t < 18) Ws9[t - 9] = W[t - 9];
  __syncthreads();
  int gid = blockIdx.x * 256 + t;      // b*NN + n
  int b = gid >> 11, n = gid & (NN - 1);
  const float4* xp = (const float4*)(xs4 + (size_t)b * NN * 4);
  float4 me = xp[n];
  float u0 = Ms[0] * me.x + Ms[1] * me.y + Ms[2] * me.z;
  float u1 = Ms[3] * me.x + Ms[4] * me.y + Ms[5] * me.z;
  float u2 = Ms[6] * me.x + Ms[7] * me.y + Ms[8] * me.z;
  const float scale = 0.57735026919f;  // 1/sqrt(3)
  const int* ip = idx + (size_t)gid * KNB;
  float nbx[KNB], nby[KNB], nbz[KNB], sc[KNB];
#pragma unroll
  for (int k = 0; k < KNB; ++k) {
    int m = ip[k] & (NN - 1);
    float4 c = xp[m];
    nbx[k] = c.x; nby[k] = c.y; nbz[k] = c.z;
    sc[k] = (c.x * u0 + c.y * u1 + c.z * u2) * scale;
  }
  float mx = sc[0];
#pragma unroll
  for (int k = 1; k < KNB; ++k) mx = fmaxf(mx, sc[k]);
  float sum = 0.f;
#pragma unroll
  for (int k = 0; k < KNB; ++k) { sc[k] = expf(sc[k] - mx); sum += sc[k]; }
  float inv = 1.f / sum;
  float a0 = 0.f, a1 = 0.f, a2 = 0.f;
#pragma unroll
  for (int k = 0; k < KNB; ++k) { a0 += sc[k] * nbx[k]; a1 += sc[k] * nby[k]; a2 += sc[k] * nbz[k]; }
  a0 = a0 * inv - me.x; a1 = a1 * inv - me.y; a2 = a2 * inv - me.z;
  float* zb = z + (size_t)b * 3 * NN;
  zb[n]          = Ws9[0] * a0 + Ws9[1] * a1 + Ws9[2] * a2;
  zb[NN + n]     = Ws9[3] * a0 + Ws9[4] * a1 + Ws9[5] * a2;
  zb[2 * NN + n] = Ws9[6] * a0 + Ws9[7] * a1 + Ws9[8] * a2;
}

// ---------------------------------------------------------------- conv GEMM 64-tile (small O)
template <bool BT, bool TOUT>
__global__ __launch_bounds__(256, 2) void conv_gemm_kernel(
    const float* __restrict__ in, int inBS, int C, int O,
    const float* __restrict__ w, float* __restrict__ z) {
  const int b = blockIdx.z;
  const int n0 = blockIdx.x * 64, o0 = blockIdx.y * 64;
  const int tid = threadIdx.x;
  const int tm = tid & 15, tn = tid >> 4;
  __shared__ float Ws[16][68];
  __shared__ float Xs[16][64];
  const float* ib = in + (size_t)b * inBS;
  float acc[4][4];
#pragma unroll
  for (int i = 0; i < 4; ++i)
#pragma unroll
    for (int j = 0; j < 4; ++j) acc[i][j] = 0.f;

  for (int k0 = 0; k0 < C; k0 += 16) {
    __syncthreads();
#pragma unroll
    for (int it = 0; it < 4; ++it) {
      int i = it * 256 + tid;
      if (BT) {
        int kc = i & 15, nl = i >> 4;
        Xs[kc][nl] = ((k0 + kc) < C) ? ib[(size_t)(n0 + nl) * C + k0 + kc] : 0.f;
      } else {
        int kc = i >> 6, nl = i & 63;
        Xs[kc][nl] = ((k0 + kc) < C) ? ib[(size_t)(k0 + kc) * NN + n0 + nl] : 0.f;
      }
      int ol = i >> 4, kc2 = i & 15;
      Ws[kc2][ol] = ((o0 + ol) < O && (k0 + kc2) < C) ? w[(size_t)(o0 + ol) * C + k0 + kc2] : 0.f;
    }
    __syncthreads();
#pragma unroll
    for (int kc = 0; kc < 16; ++kc) {
      float4 a = *(const float4*)&Ws[kc][tn * 4];
      float4 bv = *(const float4*)&Xs[kc][tm * 4];
      acc[0][0] += a.x * bv.x; acc[0][1] += a.x * bv.y; acc[0][2] += a.x * bv.z; acc[0][3] += a.x * bv.w;
      acc[1][0] += a.y * bv.x; acc[1][1] += a.y * bv.y; acc[1][2] += a.y * bv.z; acc[1][3] += a.y * bv.w;
      acc[2][0] += a.z * bv.x; acc[2][1] += a.z * bv.y; acc[2][2] += a.z * bv.z; acc[2][3] += a.z * bv.w;
      acc[3][0] += a.w * bv.x; acc[3][1] += a.w * bv.y; acc[3][2] += a.w * bv.z; acc[3][3] += a.w * bv.w;
    }
  }
  if (TOUT) {
#pragma unroll
    for (int j = 0; j < 4; ++j) {
      int n = n0 + tm * 4 + j;
      int ob = o0 + tn * 4;
      if (ob < O) {
        float4 ov;
        ov.x = acc[0][j]; ov.y = acc[1][j]; ov.z = acc[2][j]; ov.w = acc[3][j];
        *(float4*)&z[((size_t)b * NN + n) * O + ob] = ov;
      }
    }
  } else {
#pragma unroll
    for (int i = 0; i < 4; ++i) {
      int o = o0 + tn * 4 + i;
      if (o < O) {
        float4 ov;
        ov.x = acc[i][0]; ov.y = acc[i][1]; ov.z = acc[i][2]; ov.w = acc[i][3];
        *(float4*)&z[((size_t)b * O + o) * NN + n0 + tm * 4] = ov;
      }
    }
  }
}

// ---------------------------------------------------------------- conv GEMM 128-tile, double-buffered (fp32)
__global__ __launch_bounds__(256, 2) void conv_gemm128_db_kernel(
    const float* __restrict__ in, int inBS, int C, int O,
    const float* __restrict__ w, float* __restrict__ z) {
  const int b = blockIdx.z;
  const int n0 = blockIdx.x * 128, o0 = blockIdx.y * 128;
  const int tid = threadIdx.x;
  const int tm = tid & 15, tn = tid >> 4;
  __shared__ float Xs[2][16][128];
  __shared__ float Ws[2][16][132];
  const float* ib = in + (size_t)b * inBS;
  float acc[8][8];
#pragma unroll
  for (int i = 0; i < 8; ++i)
#pragma unroll
    for (int j = 0; j < 8; ++j) acc[i][j] = 0.f;

  float4 xr[2], wr[2];
  auto load_tile = [&](int k0) {
#pragma unroll
    for (int it = 0; it < 2; ++it) {
      int i = it * 256 + tid;
      int kc = i >> 5, c4 = i & 31;
      xr[it] = ((k0 + kc) < C) ? *(const float4*)&ib[(size_t)(k0 + kc) * NN + n0 + c4 * 4]
                               : make_float4(0.f, 0.f, 0.f, 0.f);
      int ol = i >> 2, kq = i & 3;
      wr[it] = ((k0 + kq * 4) < C) ? *(const float4*)&w[(size_t)(o0 + ol) * C + k0 + kq * 4]
                                   : make_float4(0.f, 0.f, 0.f, 0.f);
    }
  };
  auto store_tile = [&](int buf) {
#pragma unroll
    for (int it = 0; it < 2; ++it) {
      int i = it * 256 + tid;
      int kc = i >> 5, c4 = i & 31;
      *(float4*)&Xs[buf][kc][c4 * 4] = xr[it];
      int ol = i >> 2, kq = i & 3;
      Ws[buf][kq * 4 + 0][ol] = wr[it].x;
      Ws[buf][kq * 4 + 1][ol] = wr[it].y;
      Ws[buf][kq * 4 + 2][ol] = wr[it].z;
      Ws[buf][kq * 4 + 3][ol] = wr[it].w;
    }
  };

  load_tile(0);
  store_tile(0);
  int cur = 0;
  for (int k0 = 0; k0 < C; k0 += 16) {
    bool more = (k0 + 16) < C;
    if (more) load_tile(k0 + 16);
    __syncthreads();
#pragma unroll
    for (int kc = 0; kc < 16; ++kc) {
      float4 a0 = *(const float4*)&Ws[cur][kc][tn * 4];
      float4 a1 = *(const float4*)&Ws[cur][kc][64 + tn * 4];
      float4 b0 = *(const float4*)&Xs[cur][kc][tm * 4];
      float4 b1 = *(const float4*)&Xs[cur][kc][64 + tm * 4];
      float ar[8] = {a0.x, a0.y, a0.z, a0.w, a1.x, a1.y, a1.z, a1.w};
      float br[8] = {b0.x, b0.y, b0.z, b0.w, b1.x, b1.y, b1.z, b1.w};
#pragma unroll
      for (int i = 0; i < 8; ++i)
#pragma unroll
        for (int j = 0; j < 8; ++j) acc[i][j] += ar[i] * br[j];
    }
    if (more) store_tile(cur ^ 1);
    cur ^= 1;
  }
#pragma unroll
  for (int h = 0; h < 2; ++h)
#pragma unroll
    for (int i = 0; i < 4; ++i) {
      int r = h * 4 + i;
      int o = o0 + h * 64 + tn * 4 + i;
      float* zrow = &z[((size_t)b * O + o) * NN + n0];
      float4 o0v, o1v;
      o0v.x = acc[r][0]; o0v.y = acc[r][1]; o0v.z = acc[r][2]; o0v.w = acc[r][3];
      o1v.x = acc[r][4]; o1v.y = acc[r][5]; o1v.z = acc[r][6]; o1v.w = acc[r][7];
      *(float4*)&zrow[tm * 4] = o0v;
      *(float4*)&zrow[64 + tm * 4] = o1v;
    }
}

// ---------------------------------------------------------------- attention, register-resident (C=64/128)
template <int C, bool BF16OUT>
__global__ __launch_bounds__(256) void att_wave_reg_kernel(
    const float* __restrict__ xT, const float* __restrict__ UT,
    const int* __restrict__ idx, float* __restrict__ AGGt,
    unsigned short* __restrict__ AGGtb) {
  const int lane = threadIdx.x & 63;
  const int gid = blockIdx.x * 4 + (threadIdx.x >> 6);   // = b*NN + n
  const int n = gid & (NN - 1);
  const int b = gid >> 11;
  const float* xTb = xT + (size_t)b * NN * C;
  int nv = idx[(size_t)gid * KNB + (lane < KNB ? lane : 0)];
  float u0 = UT[(size_t)gid * C + lane];
  float u1;
  if (C == 128) u1 = UT[(size_t)gid * C + 64 + lane];
  float v0[KNB], v1[KNB], p[KNB];
#pragma unroll
  for (int k = 0; k < KNB; ++k) {
    int m = __shfl(nv, k) & (NN - 1);
    v0[k] = xTb[(size_t)m * C + lane];
    if (C == 128) v1[k] = xTb[(size_t)m * C + 64 + lane];
  }
#pragma unroll
  for (int k = 0; k < KNB; ++k) {
    float a = v0[k] * u0;
    if (C == 128) a += v1[k] * u1;
    p[k] = a;
  }
#pragma unroll
  for (int k = 0; k < KNB; ++k) {
#pragma unroll
    for (int s = 32; s > 0; s >>= 1) p[k] += __shfl_xor(p[k], s);
  }
  const float scale = (C == 128) ? 0.088388347648318447f : 0.125f;  // 1/sqrt(C)
  float mx = p[0];
#pragma unroll
  for (int k = 1; k < KNB; ++k) mx = fmaxf(mx, p[k]);
  float sum = 0.f;
#pragma unroll
  for (int k = 0; k < KNB; ++k) {
    p[k] = expf((p[k] - mx) * scale);
    sum += p[k];
  }
  float inv = 1.f / sum;
  float a0 = 0.f, a1 = 0.f;
#pragma unroll
  for (int k = 0; k < KNB; ++k) {
    a0 += p[k] * v0[k];
    if (C == 128) a1 += p[k] * v1[k];
  }
  float r0 = a0 * inv - xTb[(size_t)n * C + lane];
  float r1;
  if (C == 128) r1 = a1 * inv - xTb[(size_t)n * C + 64 + lane];
  if (BF16OUT) {
    AGGtb[(size_t)gid * C + lane] = f2bf(r0);
    if (C == 128) AGGtb[(size_t)gid * C + 64 + lane] = f2bf(r1);
  } else {
    AGGt[(size_t)gid * C + lane] = r0;
    if (C == 128) AGGt[(size_t)gid * C + 64 + lane] = r1;
  }
}

// ---------------------------------------------------------------- fused BN (+LReLU), float4
template <bool PRE>
__global__ __launch_bounds__(256) void bn_fused_kernel(const float* __restrict__ z, int O,
                                                       float* __restrict__ out, int outBS, int c0,
                                                       const float* __restrict__ gs) {
  int o = blockIdx.x;
  int tid = threadIdx.x;
  float m, r;
  if (PRE) {
    float s = gs[o * 2], s2 = gs[o * 2 + 1];
    m = s / (BB * NN);
    float var = s2 / (BB * NN) - m * m;
    r = rsqrtf(var + 1e-5f);
  } else {
    __shared__ float s1[256], s2[256];
    __shared__ float smv, srv;
    float a1 = 0.f, a2 = 0.f;
    for (int i = tid; i < BB * 512; i += 256) {
      int b = i >> 9, n4 = i & 511;
      float4 v = *(const float4*)&z[((size_t)b * O + o) * NN + n4 * 4];
      a1 += v.x + v.y + v.z + v.w;
      a2 += v.x * v.x + v.y * v.y + v.z * v.z + v.w * v.w;
    }
    s1[tid] = a1; s2[tid] = a2;
    __syncthreads();
    for (int st = 128; st > 0; st >>= 1) {
      if (tid < st) { s1[tid] += s1[tid + st]; s2[tid] += s2[tid + st]; }
      __syncthreads();
    }
    if (tid == 0) {
      float mm = s1[0] / (BB * NN);
      float var = s2[0] / (BB * NN) - mm * mm;
      smv = mm; srv = rsqrtf(var + 1e-5f);
    }
    __syncthreads();
    m = smv; r = srv;
  }
  for (int i = tid; i < BB * 512; i += 256) {
    int b = i >> 9, n4 = i & 511;
    float4 v = *(const float4*)&z[((size_t)b * O + o) * NN + n4 * 4];
    float4 ov;
    ov.x = lrelu((v.x - m) * r); ov.y = lrelu((v.y - m) * r);
    ov.z = lrelu((v.z - m) * r); ov.w = lrelu((v.w - m) * r);
    *(float4*)&out[(size_t)b * outBS + (size_t)(c0 + o) * NN + n4 * 4] = ov;
  }
}

// ---------------------------------------------------------------- BN+LReLU into h[:,0:O,:], copy xin into h[:,O:2O,:], float4
__global__ __launch_bounds__(256) void bn_copy_kernel(const float* __restrict__ z, int O,
                                                      const float* __restrict__ xin, int xbs,
                                                      float* __restrict__ out) {
  int o = blockIdx.x;  // 0..2O-1
  int tid = threadIdx.x;
  int outBS = 2 * O * NN;
  if (o >= O) {
    int c = o - O;
    for (int i = tid; i < BB * 512; i += 256) {
      int b = i >> 9, n4 = i & 511;
      *(float4*)&out[(size_t)b * outBS + (size_t)o * NN + n4 * 4] =
          *(const float4*)&xin[(size_t)b * xbs + (size_t)c * NN + n4 * 4];
    }
    return;
  }
  __shared__ float s1[256], s2[256];
  __shared__ float smv, srv;
  float a1 = 0.f, a2 = 0.f;
  for (int i = tid; i < BB * 512; i += 256) {
    int b = i >> 9, n4 = i & 511;
    float4 v = *(const float4*)&z[((size_t)b * O + o) * NN + n4 * 4];
    a1 += v.x + v.y + v.z + v.w;
    a2 += v.x * v.x + v.y * v.y + v.z * v.z + v.w * v.w;
  }
  s1[tid] = a1; s2[tid] = a2;
  __syncthreads();
  for (int st = 128; st > 0; st >>= 1) {
    if (tid < st) { s1[tid] += s1[tid + st]; s2[tid] += s2[tid + st]; }
    __syncthreads();
  }
  if (tid == 0) {
    float m = s1[0] / (BB * NN);
    float var = s2[0] / (BB * NN) - m * m;
    smv = m; srv = rsqrtf(var + 1e-5f);
  }
  __syncthreads();
  float m = smv, r = srv;
  for (int i = tid; i < BB * 512; i += 256) {
    int b = i >> 9, n4 = i & 511;
    float4 v = *(const float4*)&z[((size_t)b * O + o) * NN + n4 * 4];
    float4 ov;
    ov.x = lrelu((v.x - m) * r); ov.y = lrelu((v.y - m) * r);
    ov.z = lrelu((v.z - m) * r); ov.w = lrelu((v.w - m) * r);
    *(float4*)&out[(size_t)b * outBS + (size_t)o * NN + n4 * 4] = ov;
  }
}

// ---------------------------------------------------------------- fused BN+LReLU+max/mean pool (conv5), float4
template <bool PRE>
__global__ __launch_bounds__(256) void bn_pool_kernel(const float* __restrict__ z,
                                                      float* __restrict__ p,
                                                      const float* __restrict__ gs) {
  int o = blockIdx.x;
  int tid = threadIdx.x;
  float m, r;
  if (PRE) {
    float s = gs[o * 2], s2 = gs[o * 2 + 1];
    m = s / (BB * NN);
    float var = s2 / (BB * NN) - m * m;
    r = rsqrtf(var + 1e-5f);
  } else {
    __shared__ float s1[256], s2[256];
    __shared__ float smv, srv;
    float a1 = 0.f, a2 = 0.f;
    for (int i = tid; i < BB * 512; i += 256) {
      int b = i >> 9, n4 = i & 511;
      float4 v = *(const float4*)&z[((size_t)b * 1024 + o) * NN + n4 * 4];
      a1 += v.x + v.y + v.z + v.w;
      a2 += v.x * v.x + v.y * v.y + v.z * v.z + v.w * v.w;
    }
    s1[tid] = a1; s2[tid] = a2;
    __syncthreads();
    for (int st = 128; st > 0; st >>= 1) {
      if (tid < st) { s1[tid] += s1[tid + st]; s2[tid] += s2[tid + st]; }
      __syncthreads();
    }
    if (tid == 0) {
      float mm = s1[0] / (BB * NN);
      float var = s2[0] / (BB * NN) - mm * mm;
      smv = mm; srv = rsqrtf(var + 1e-5f);
    }
    __syncthreads();
    m = smv; r = srv;
  }
  int b = tid >> 5, l = tid & 31;
  const float* zp = z + ((size_t)b * 1024 + o) * NN;
  float mx = -INFINITY, sm = 0.f;
  for (int j = l; j < 512; j += 32) {
    float4 v = *(const float4*)&zp[j * 4];
    float vx = lrelu((v.x - m) * r), vy = lrelu((v.y - m) * r);
    float vz = lrelu((v.z - m) * r), vw = lrelu((v.w - m) * r);
    mx = fmaxf(mx, fmaxf(fmaxf(vx, vy), fmaxf(vz, vw)));
    sm += vx + vy + vz + vw;
  }
#pragma unroll
  for (int s = 16; s > 0; s >>= 1) {
    mx = fmaxf(mx, __shfl_xor(mx, s));
    sm += __shfl_xor(sm, s);
  }
  if (l == 0) {
    p[b * 2048 + o] = mx;
    p[b * 2048 + 1024 + o] = sm * (1.f / NN);
  }
}

__global__ __launch_bounds__(64) void linear_kernel(const float* __restrict__ in, int IN, int OUT,
                                                    const float* __restrict__ w,
                                                    const float* __restrict__ bias,
                                                    float* __restrict__ out) {
  int o = blockIdx.x;
  int b = o / OUT, f = o % OUT;
  const float* ip = in + (size_t)b * IN;
  const float* wp = w + (size_t)f * IN;
  float a = 0.f;
  for (int i = threadIdx.x; i < IN; i += 64) a += ip[i] * wp[i];
#pragma unroll
  for (int s = 32; s > 0; s >>= 1) a += __shfl_down(a, s);
  if (threadIdx.x == 0) out[o] = a + bias[f];
}

__global__ __launch_bounds__(256) void bnf_kernel(float* __restrict__ t, int F) {
  int f = blockIdx.x * blockDim.x + threadIdx.x;
  if (f >= F) return;
  float s = 0.f, s2 = 0.f;
  for (int b = 0; b < BB; ++b) { float v = t[b * F + f]; s += v; s2 += v * v; }
  float m = s * (1.f / BB);
  float var = s2 * (1.f / BB) - m * m;
  float r = rsqrtf(var + 1e-5f);
  for (int b = 0; b < BB; ++b) {
    float v = (t[b * F + f] - m) * r;
    t[b * F + f] = v >= 0.f ? v : 0.2f * v;
  }
}

// ---------------------------------------------------------------- host side

struct SAW { const float *wq, *wk, *wv, *wc; };

static inline void run_conv(const float* in, int inBS, int C, int O, const float* w,
                            float* z, hipStream_t st) {
  if (O % 128 == 0)
    conv_gemm128_db_kernel<<<dim3(NN / 128, O / 128, BB), 256, 0, st>>>(in, inBS, C, O, w, z);
  else
    conv_gemm_kernel<false, false><<<dim3(NN / 64, (O + 63) / 64, BB), 256, 0, st>>>(in, inBS, C, O, w, z);
}

// C=64/128 path. Weights (M/WCV/Mb/wcvb) precomputed upfront.
template <int C, bool MFMA>
static inline void run_sa(const float* xin, int xbs,
                          float* xT, float* UT, float* AGGt, float* z, float* h,
                          float* sq, int* idx,
                          const float* M, const float* WCV,
                          const unsigned short* Mb, const unsigned short* wcvb,
                          unsigned short* xTb, unsigned short* AGGtb,
                          _Float16* xhi, _Float16* xlo,
                          float* D, int nbatch, hipStream_t st) {
  static_assert(C % 32 == 0, "run_sa requires C % 32 == 0");
  xprep_kernel<true, MFMA><<<dim3(NN / 32, C / 32, BB), 256, 0, st>>>(
      xin, xbs, C, xT, xhi, xlo, xTb, sq);
  for (int bb = 0; bb < BB; bb += nbatch) {
    int nbc = (BB - bb) < nbatch ? (BB - bb) : nbatch;
    pd_mfma_sym_kernel<<<dim3(136, nbc), 256, 0, st>>>(xhi, xlo, C, sq, D, bb);
    topk_bsort_kernel<<<dim3(NN / 4, nbc), 256, 0, st>>>(D, idx, bb);
  }
  if (MFMA) {
    mfma_gemm_lds_kernel<true, false><<<dim3(NN / 128, C / 128, BB), 256, 0, st>>>(
        (const unsigned short*)Mb, xTb, UT, C, C, nullptr);
    att_wave_reg_kernel<C, true><<<BB * NN / 4, 256, 0, st>>>(xT, UT, idx, nullptr, AGGtb);
    mfma_gemm_lds_kernel<false, false><<<dim3(NN / 128, C / 128, BB), 256, 0, st>>>(
        (const unsigned short*)wcvb, AGGtb, z, C, C, nullptr);
  } else {
    conv_gemm_kernel<false, true><<<dim3(NN / 64, C / 64, BB), 256, 0, st>>>(xin, xbs, C, C, M, UT);
    att_wave_reg_kernel<C, false><<<BB * NN / 4, 256, 0, st>>>(xT, UT, idx, AGGt, nullptr);
    conv_gemm_kernel<true, false><<<dim3(NN / 64, C / 64, BB), 256, 0, st>>>(AGGt, NN * C, C, C, WCV, z);
  }
  bn_copy_kernel<<<2 * C, 256, 0, st>>>(z, C, xin, xbs, h);
}

// SA1 (C=3): everything fused.
static inline void run_sa3(const float* xin, float* z, float* h, float* xs4, int* idx,
                           const float* M, const float* WCV, hipStream_t st) {
  xprep3_kernel<<<dim3(NN / 256, 1, BB), 256, 0, st>>>(xin, xs4);
  topk_c3_kernel<<<dim3(NN / 4, BB), 256, 0, st>>>(xs4, idx);
  sa1_fused_kernel<<<BB * NN / 256, 256, 0, st>>>(xs4, idx, M, WCV, z);
  bn_copy_kernel<<<6, 256, 0, st>>>(z, 3, xin, 3 * NN, h);
}

static inline void run_conv_bn(const float* in, int inBS, int Cin, int O, const float* w,
                               float* z, float* out, int outBS, int c0, hipStream_t st) {
  run_conv(in, inBS, Cin, O, w, z, st);
  bn_fused_kernel<false><<<O, 256, 0, st>>>(z, O, out, outBS, c0, nullptr);
}

extern "C" void kernel_launch(void* const* d_in, const int* in_sizes, int n_in,
                              void* d_out, int out_size, void* d_ws, size_t ws_size,
                              hipStream_t stream) {
  const float* x = (const float*)d_in[0];
  SAW sa1{(const float*)d_in[1], (const float*)d_in[2], (const float*)d_in[3], (const float*)d_in[4]};
  SAW sa2{(const float*)d_in[5], (const float*)d_in[6], (const float*)d_in[7], (const float*)d_in[8]};
  SAW sa3{(const float*)d_in[9], (const float*)d_in[10], (const float*)d_in[11], (const float*)d_in[12]};
  SAW sa4{(const float*)d_in[13], (const float*)d_in[14], (const float*)d_in[15], (const float*)d_in[16]};
  const float* conv1_w = (const float*)d_in[17];
  const float* conv2_w = (const float*)d_in[18];
  const float* conv3_w = (const float*)d_in[19];
  const float* conv4_w = (const float*)d_in[20];
  const float* conv5_w = (const float*)d_in[21];
  const float* lin1_w = (const float*)d_in[22];
  const float* lin1_b = (const float*)d_in[23];
  const float* lin2_w = (const float*)d_in[24];
  const float* lin2_b = (const float*)d_in[25];
  const float* lin3_w = (const float*)d_in[26];
  const float* lin3_b = (const float*)d_in[27];

  char* ws = (char*)d_ws;
  size_t off = 0;
  auto take = [&](size_t bytes) -> void* {
    void* p = ws + off;
    off += (bytes + 255) & ~(size_t)255;
    return p;
  };
  float* sqR  = (float*)take((size_t)3 * BB * NN * 4);       // SA2/3/4 sq, zeroed once
  float* statsR = (float*)take((size_t)(256 + 1024) * 2 * 4); // conv4+conv5 BN stats (contig w/ sqR)
  float* xs4  = (float*)take((size_t)BB * NN * 4 * 4);       // SA1 {x,y,z,sq}
  int*   idx  = (int*)take((size_t)BB * NN * KNB * 4);
  float* Mall = (float*)take((size_t)4 * 128 * 128 * 4);     // per-SA M
  float* Wall = (float*)take((size_t)4 * 128 * 128 * 4);     // per-SA WCV
  unsigned short* Mb4   = (unsigned short*)take((size_t)128 * 128 * 2);
  unsigned short* wcvb4 = (unsigned short*)take((size_t)128 * 128 * 2);
  unsigned short* w4b  = (unsigned short*)take((size_t)256 * 256 * 2);
  unsigned short* w5b  = (unsigned short*)take((size_t)1024 * 512 * 2);
  float* U    = (float*)take((size_t)BB * 128 * NN * 4);  // conv4-5 bf16 overlays
  float* AGG  = (float*)take((size_t)BB * 128 * NN * 4);  // hosts xT (+ AGGt for SA2/3)
  float* h    = (float*)take((size_t)BB * 256 * NN * 4);  // overlays below
  float* z    = (float*)take((size_t)BB * 1024 * NN * 4); // hosts AGGtb(+16MB), D-chunks
  float* xc   = (float*)take((size_t)BB * 512 * NN * 4);
  float* p    = (float*)take((size_t)BB * 2048 * 4);
  float* t1   = (float*)take((size_t)BB * 512 * 4);
  float* t2   = (float*)take((size_t)BB * 256 * 4);
  (void)n_in; (void)in_sizes; (void)out_size;

  float* M1 = Mall + 0 * 16384; float* W1 = Wall + 0 * 16384;
  float* M2 = Mall + 1 * 16384; float* W2 = Wall + 1 * 16384;
  float* M3 = Mall + 2 * 16384; float* W3 = Wall + 2 * 16384;
  float* M4 = Mall + 3 * 16384; float* W4 = Wall + 3 * 16384;
  float* stats4 = statsR;            // 256 ch
  float* stats5 = statsR + 256 * 2;  // 1024 ch

  // Overlays (phase-ordered lifetimes):
  float* xT = AGG;                                          // first half of AGG (C<=128)
  float* AGGt64 = AGG + (size_t)BB * NN * 64;               // SA2/3 AGGt [n][64] (2nd half of AGG)
  float* UT = h;                                            // consumed before h written
  unsigned short* xTb   = (unsigned short*)((char*)h + (size_t)BB * 128 * NN * 4);  // h 2nd half
  unsigned short* AGGtb = (unsigned short*)((char*)z + (size_t)16 * 1024 * 1024);   // z + 16 MB
  unsigned short* hTb   = (unsigned short*)U;               // conv4 phase (U dead)
  unsigned short* xcTb  = (unsigned short*)U;               // conv5 phase (U dead, 16.8 MB)
  _Float16* xhi = (_Float16*)h;                             // pd phase only (UT written after)
  _Float16* xlo = (_Float16*)((char*)h + (size_t)BB * NN * 128 * 2);

  size_t dfull = (size_t)BB * NN * NN * 4;
  bool fullD = (ws_size > off + dfull + 4096);
  float* D = fullD ? (float*)take(dfull) : z;               // !fullD: 4-batch chunks fill z exactly
  int nbatch = fullD ? BB : 4;

  // One upfront zero for sq regions + BN stats (contiguous takes).
  hipMemsetAsync(sqR, 0, (size_t)3 * BB * NN * 4 + (size_t)(256 + 1024) * 2 * 4, stream);
  // All weight-derived tensors in one launch (no activation deps).
  weight_prep_kernel<<<5 + 2048 + 2048 + 8192 + 256 + 2048, 256, 0, stream>>>(
      sa1.wq, sa1.wk, sa1.wv, sa1.wc, sa2.wq, sa2.wk, sa2.wv, sa2.wc,
      sa3.wq, sa3.wk, sa3.wv, sa3.wc, sa4.wq, sa4.wk, sa4.wv, sa4.wc,
      conv4_w, conv5_w, M1, W1, M2, W2, M3, W3, M4, W4, Mb4, wcvb4, w4b, w5b);

  // SA1 (C=3) -> h [B,6,N]  (fully fused)
  run_sa3(x, z, h, xs4, idx, M1, W1, stream);
  run_conv_bn(h, 6 * NN, 6, 64, conv1_w, z, xc, 512 * NN, 0, stream);
  // SA2 (C=64) on x1
  run_sa<64, false>(xc + 0 * NN, 512 * NN, xT, UT, AGGt64, z, h,
                    sqR + 0 * BB * NN, idx, M2, W2, nullptr, nullptr, xTb, AGGtb, xhi, xlo,
                    D, nbatch, stream);
  run_conv_bn(h, 128 * NN, 128, 64, conv2_w, z, xc, 512 * NN, 64, stream);
  // SA3 (C=64) on x2
  run_sa<64, false>(xc + 64 * NN, 512 * NN, xT, UT, AGGt64, z, h,
                    sqR + 1 * BB * NN, idx, M3, W3, nullptr, nullptr, xTb, AGGtb, xhi, xlo,
                    D, nbatch, stream);
  run_conv_bn(h, 128 * NN, 128, 128, conv3_w, z, xc, 512 * NN, 128, stream);
  // SA4 (C=128) on x3 — bf16 MFMA for U and Z convs
  run_sa<128, true>(xc + 128 * NN, 512 * NN, xT, UT, nullptr, z, h,
                    sqR + 2 * BB * NN, idx, M4, W4, Mb4, wcvb4, xTb, AGGtb, xhi, xlo,
                    D, nbatch, stream);
  // conv4 (bf16 MFMA + fused BN stats): h [B,256,N] -> z [B,256,N]
  transpose_bf16_kernel<<<dim3(NN / 32, 8, BB), 256, 0, stream>>>(h, 256 * NN, 256, NN, hTb);
  mfma_gemm_lds_kernel<false, true><<<dim3(NN / 128, 2, BB), 256, 0, stream>>>(
      w4b, hTb, z, 256, 256, stats4);
  bn_fused_kernel<true><<<256, 256, 0, stream>>>(z, 256, xc, 512 * NN, 256, stats4);
  // conv5 (bf16 MFMA, 256x128 tile + fused BN stats): xc [B,512,N] -> z [B,1024,N]
  transpose_bf16_kernel<<<dim3(NN / 32, 16, BB), 256, 0, stream>>>(xc, 512 * NN, 512, NN, xcTb);
  mfma_gemm_n256_kernel<<<dim3(NN / 256, 8, BB), 256, 0, stream>>>(
      w5b, xcTb, z, 1024, 512, stats5);
  bn_pool_kernel<true><<<1024, 256, 0, stream>>>(z, p, stats5);
  // FC head
  linear_kernel<<<BB * 512, 64, 0, stream>>>(p, 2048, 512, lin1_w, lin1_b, t1);
  bnf_kernel<<<2, 256, 0, stream>>>(t1, 512);
  linear_kernel<<<BB * 256, 64, 0, stream>>>(t1, 512, 256, lin2_w, lin2_b, t2);
  bnf_kernel<<<1, 256, 0, stream>>>(t2, 256);
  linear_kernel<<<BB * 40, 64, 0, stream>>>(t2, 256, 40, lin3_w, lin3_b, (float*)d_out);
}